// Round 15
// baseline (1781.455 us; speedup 1.0000x reference)
//
#include <hip/hip_runtime.h>

typedef unsigned short u16;
typedef __bf16 bf16x8 __attribute__((ext_vector_type(8)));
typedef float f32x4 __attribute__((ext_vector_type(4)));

#define DEV __device__ __forceinline__

DEV u16 f2b(float f){
  union { float f; unsigned u; } v; v.f = f;
  unsigned r = v.u + 0x7FFFu + ((v.u >> 16) & 1u);
  return (u16)(r >> 16);
}
DEV float b2f(u16 h){
  union { unsigned u; float f; } v; v.u = ((unsigned)h) << 16; return v.f;
}

DEV f32x4 zero4(){ f32x4 z; z[0]=0.f; z[1]=0.f; z[2]=0.f; z[3]=0.f; return z; }

// async 16B global -> LDS (dest = wave-uniform base + lane*16)
DEV void gload16(const u16* g, const u16* l){
  __builtin_amdgcn_global_load_lds(
      (const __attribute__((address_space(1))) unsigned int*)g,
      (__attribute__((address_space(3))) unsigned int*)l, 16, 0, 0);
}

// ---------------- transpose + fp32->bf16: dst[n*K+k] = bf16(src[k*N+n]) -----
template<int K, int N, long long DSTR>
__global__ __launch_bounds__(256) void transpose_k(const float* __restrict__ src,
                                                   u16* __restrict__ dst){
  __shared__ float tile[32][33];
  const int z = blockIdx.z;
  const float* s = src + (size_t)z*K*N;
  u16* d = dst + (size_t)z*DSTR;
  const int k0 = blockIdx.x*32, n0 = blockIdx.y*32;
  const int tx = threadIdx.x & 31, ty = threadIdx.x >> 5;
  #pragma unroll
  for (int j=0;j<32;j+=8) tile[ty+j][tx] = s[(size_t)(k0+ty+j)*N + n0+tx];
  __syncthreads();
  #pragma unroll
  for (int j=0;j<32;j+=8) d[(size_t)(n0+ty+j)*K + k0+tx] = f2b(tile[tx][ty+j]);
}

// ---------------- bias concat for fused QKV --------------------------------
__global__ __launch_bounds__(256) void concat_bias(const float* __restrict__ bq,
    const float* __restrict__ bk, const float* __restrict__ bv,
    float* __restrict__ bcat){
  int i = blockIdx.x*256 + threadIdx.x;            // over 6*1536
  int l = i / 1536, c = i % 1536;
  float v = (c < 512) ? bq[l*512 + c]
          : (c < 1024) ? bk[l*512 + c - 512]
                       : bv[l*512 + c - 1024];
  bcat[i] = v;
}

// ------- embedding (vectorized 8/thread): x = traj@W_emb + b_emb + pe -------
__global__ __launch_bounds__(256) void embed_kernel(const float* __restrict__ traj,
    const float* __restrict__ We, const float* __restrict__ be,
    const float* __restrict__ pe, u16* __restrict__ xb){
  size_t g = (size_t)blockIdx.x*256 + threadIdx.x;   // over 25600*64 groups
  const int d0 = (int)(g & 63) * 8;
  const size_t tk = g >> 6;
  const float t0 = traj[tk*2], t1 = traj[tk*2+1];
  union { u16 pk[8]; uint4 v; } u;
  #pragma unroll
  for (int j=0;j<8;j++){
    const int d = d0 + j;
    u.pk[j] = f2b(t0*We[d] + t1*We[512+d] + be[d] + pe[200*512 + d]);
  }
  *(uint4*)&xb[tk*512 + d0] = u.v;
}

// ===================== 256x256 8-phase GEMM (T2+T3+T4+T5) ====================
// R13 trunk (best: 1627 us). Hard session constraints:
//  - acc[8][4]=128 regs + ~124 VGPR = 252/wave; 2x252=504<=512 -> 2 waves/SIMD
//    hard cap, 8 VGPR total headroom (R7 disaster; no A-frag dbuf possible).
//  - ceil(tiles/256)*T makespan is a hard LB; grid games can't beat it (R10).
//  - fine 8-phase interleave required; merging phases regresses (R4 == m196).
//  - trailing barrier only at P4/P8 (publication points); others redundant (R13).
template<int K, int NTI, bool RELU>
__global__ __launch_bounds__(512, 2) void gemm256(const u16* __restrict__ A,
    const u16* __restrict__ Bt, const float* __restrict__ bias,
    u16* __restrict__ outp, int nwg){
  constexpr int N = NTI*256;
  constexpr int NT = K/64;              // K-tiles (even for K=512/2048)
  __shared__ __align__(16) u16 S[65536];
  const int t = threadIdx.x, lane = t&63, w = t>>6;
  const int l16 = lane&15, g16 = lane>>4;
  const int wm = w>>2, wn = w&3;

  // bijective XCD swizzle (m204)
  const int orig = blockIdx.x;
  const int qq = nwg>>3, rr = nwg&7, xc = orig&7, oo = orig>>3;
  const int wg = (xc<rr ? xc*(qq+1) : rr*(qq+1)+(xc-rr)*qq) + oo;
  const int mt = wg / NTI, ntl = wg % NTI;
  const size_t m0 = (size_t)mt*256, n0 = (size_t)ntl*256;
  const u16* Ab = A + m0*K;
  const u16* Bb = Bt + n0*K;

  const int srow = t>>3;
  const int scol = 8*((t&7) ^ ((t>>3)&7));
  const int kx = (l16&7)<<3;            // read-side XOR (u16 units)

  // precomputed staging source pointers (rows srow, 64+srow, 128+srow, 192+srow)
  const u16* gA[4] = {Ab + (size_t)srow*K + scol,       Ab + (size_t)(64+srow)*K + scol,
                      Ab + (size_t)(128+srow)*K + scol, Ab + (size_t)(192+srow)*K + scol};
  const u16* gB[4] = {Bb + (size_t)srow*K + scol,       Bb + (size_t)(64+srow)*K + scol,
                      Bb + (size_t)(128+srow)*K + scol, Bb + (size_t)(192+srow)*K + scol};

  f32x4 acc[8][4];
  #pragma unroll
  for (int i=0;i<8;i++)
    #pragma unroll
    for (int j=0;j<4;j++) acc[i][j] = zero4();

  #define STG(gp, kb, region, half)                                         \
    { gload16(gp[2*(half)]   + (kb), &S[(region) + (half)*8192 + w*512]);   \
      gload16(gp[2*(half)+1] + (kb), &S[(region) + (half)*8192 + 4096 + w*512]); }

  // prologue: tile0 A+B (buf0), tile1 B (buf1.B); tile1 A comes in P1/P2
  STG(gA, 0, 0, 0);      STG(gA, 0, 0, 1);
  STG(gB, 0, 16384, 0);  STG(gB, 0, 16384, 1);
  STG(gB, 64, 49152, 0); STG(gB, 64, 49152, 1);
  asm volatile("s_waitcnt vmcnt(4)" ::: "memory");   // buf0 landed; b1.B in flight
  __builtin_amdgcn_s_barrier();

  bf16x8 breg[4][2];

  // ENDBAR: trailing barrier only where staged data is published (P4/P8)
  #define PHASE(AB, BB, Q, LOADB, STG_STMT, VMW, ENDBAR)                    \
  {                                                                         \
    bf16x8 af[2][2];                                                        \
    _Pragma("unroll")                                                       \
    for (int ks=0;ks<2;ks++){                                               \
      _Pragma("unroll")                                                     \
      for (int j=0;j<2;j++)                                                 \
        af[j][ks] = *(const bf16x8*)&S[(AB) + (wm*128 + (2*(Q)+j)*16 + l16)*64 \
                                        + ((ks*32 + g16*8) ^ kx)];          \
      if (LOADB){                                                           \
        _Pragma("unroll")                                                   \
        for (int ni=0;ni<4;ni++)                                            \
          breg[ni][ks] = *(const bf16x8*)&S[(BB) + (wn*64 + ni*16 + l16)*64 \
                                             + ((ks*32 + g16*8) ^ kx)];     \
      }                                                                     \
    }                                                                       \
    STG_STMT;                                                               \
    __builtin_amdgcn_s_barrier();                                           \
    __builtin_amdgcn_s_setprio(1);                                          \
    _Pragma("unroll")                                                       \
    for (int ks=0;ks<2;ks++){                                               \
      _Pragma("unroll")                                                     \
      for (int j=0;j<2;j++){                                                \
        _Pragma("unroll")                                                   \
        for (int ni=0;ni<4;ni++)                                            \
          acc[2*(Q)+j][ni] = __builtin_amdgcn_mfma_f32_16x16x32_bf16(       \
              af[j][ks], breg[ni][ks], acc[2*(Q)+j][ni], 0, 0, 0);          \
      }                                                                     \
    }                                                                       \
    __builtin_amdgcn_s_setprio(0);                                          \
    VMW;                                                                    \
    if (ENDBAR) __builtin_amdgcn_s_barrier();                               \
  }

  for (int it=0; it<NT/2; ++it){
    const bool last = (it == NT/2 - 1);
    const int k1 = 2*it+1, k2 = 2*it+2, k3 = 2*it+3;   // k2,k3 used iff !last
    // P1-P4: tile 2t from buf0; stage k1.A (->b1.A), k2.B (->b0.B)
    PHASE(0,     16384, 0, true,  STG(gA, k1*64, 32768, 0), ((void)0), 0);
    PHASE(0,     16384, 1, false, STG(gA, k1*64, 32768, 1), ((void)0), 0);
    PHASE(0,     16384, 2, false, if(!last){ STG(gB, k2*64, 16384, 0) }, ((void)0), 0);
    PHASE(0,     16384, 3, false, if(!last){ STG(gB, k2*64, 16384, 1) },
          if(last){ asm volatile("s_waitcnt vmcnt(0)" ::: "memory"); }
          else    { asm volatile("s_waitcnt vmcnt(4)" ::: "memory"); }, 1);
    // P5-P8: tile 2t+1 from buf1; stage k2.A (->b0.A), k3.B (->b1.B)
    PHASE(32768, 49152, 0, true,  if(!last){ STG(gA, k2*64, 0, 0) }, ((void)0), 0);
    PHASE(32768, 49152, 1, false, if(!last){ STG(gA, k2*64, 0, 1) }, ((void)0), 0);
    PHASE(32768, 49152, 2, false, if(!last){ STG(gB, k3*64, 49152, 0) }, ((void)0), 0);
    PHASE(32768, 49152, 3, false, if(!last){ STG(gB, k3*64, 49152, 1) },
          if(!last){ asm volatile("s_waitcnt vmcnt(4)" ::: "memory"); }, 1);
  }
  #undef PHASE
  #undef STG

  // -------- coalesced bf16 epilogue via LDS, 2 passes (4 barriers total) ----
  __syncthreads();
  float bs[4];
  #pragma unroll
  for (int ni=0;ni<4;ni++) bs[ni] = bias[n0 + wn*64 + ni*16 + l16];
  constexpr int LDE = 264;                           // 256 + 8 pad (u16)
  #pragma unroll
  for (int pass=0; pass<2; ++pass){
    const int miB = pass*4;
    #pragma unroll
    for (int miL=0; miL<4; miL++){
      #pragma unroll
      for (int ni=0;ni<4;ni++){
        #pragma unroll
        for (int i=0;i<4;i++){
          float vv = acc[miB+miL][ni][i] + bs[ni];
          if constexpr (RELU) vv = fmaxf(vv, 0.f);
          S[(wm*64 + miL*16 + 4*g16 + i)*LDE + wn*64 + ni*16 + l16] = f2b(vv);
        }
      }
    }
    __syncthreads();
    #pragma unroll
    for (int cc=0; cc<8; cc++){
      const int c = t + cc*512;            // 0..4095 (128 rows x 32 chunks)
      const int R = c >> 5, ck = c & 31;   // R: wmR*64 + miL*16 + r
      uint4 v = *(const uint4*)&S[R*LDE + ck*8];
      const size_t grow = m0 + (size_t)(R>>6)*128 + miB*16 + (R&63);
      *(uint4*)&outp[grow*N + n0 + ck*8] = v;
    }
    if (pass == 0) __syncthreads();
  }
}

// ---------------- attention: one block per (b,h) ----------------------------
// q/k/v live in the fused qkv buffer, token stride 1536 (q:+0 k:+512 v:+1024)
// R14: Vt stride 264 + XOR swizzle col ^= ((row>>3)&7)<<3 on write AND read.
// 8-aligned pad can't fix the 8-row-apart write conflict (4*stride == 0 mod 32
// for any b128-legal stride); the swizzle spreads the 8 d0-groups over banks
// {0,4,..,28}. Reader recovers V[ko+i][d] exactly -> bit-identical values.
__global__ __launch_bounds__(256) void attn_kernel(const u16* __restrict__ qkv,
    const int* __restrict__ mask, u16* __restrict__ ctx){
  __shared__ __align__(16) u16 Vt[64*264];        // V^T swizzled, zero-padded
  __shared__ __align__(16) u16 Ps[4*16*232];      // per-wave P tiles
  __shared__ float maskadd[208];
  const int bh = blockIdx.x, b = bh>>3, h = bh&7;
  const int t = threadIdx.x, lane = t&63, w = t>>6;
  const int g16 = lane>>4, l16 = lane&15;

  for (int i=t; i<2112; i+=256) ((uint4*)Vt)[i] = make_uint4(0,0,0,0);
  for (int i=t; i<1856; i+=256) ((uint4*)Ps)[i] = make_uint4(0,0,0,0);
  __syncthreads();

  // stage V^T: coalesced 16B row loads, swizzled scatter-transpose into LDS
  for (int idx = t; idx < 1600; idx += 256){
    const int s = idx >> 3, d0 = (idx & 7) * 8;
    const int key = (idx & 7) << 3;               // ((row>>3)&7)<<3, row=d0+j
    uint4 v4 = *(const uint4*)&qkv[((size_t)(b*200+s))*1536 + 1024 + h*64 + d0];
    const u16* e = (const u16*)&v4;
    #pragma unroll
    for (int j=0;j<8;j++) Vt[(d0+j)*264 + (s ^ key)] = e[j];
  }
  if (t < 208) maskadd[t] = (t < 200 && mask[b*200+t] != 0) ? 0.f : -1e30f;
  __syncthreads();

  u16* Pw = Ps + w*16*232;
  const float scale = 0.125f;   // 1/sqrt(64)

  for (int rt = w; rt < 13; rt += 4){
    const int rbase = rt*16;
    f32x4 sc[13];
    #pragma unroll
    for (int ct=0;ct<13;ct++) sc[ct] = zero4();

    #pragma unroll
    for (int ks=0; ks<64; ks+=32){
      const int ko = ks + 8*g16;
      const size_t qrow = (size_t)(b*200) + rbase + l16;
      bf16x8 aq = *(const bf16x8*)&qkv[qrow*1536 + h*64 + ko];
      #pragma unroll
      for (int ct=0; ct<13; ct++){
        const size_t krow = (size_t)(b*200) + ct*16 + l16;
        bf16x8 bk8 = *(const bf16x8*)&qkv[krow*1536 + 512 + h*64 + ko];
        sc[ct] = __builtin_amdgcn_mfma_f32_16x16x32_bf16(aq, bk8, sc[ct], 0,0,0);
      }
    }

    float mx[4] = {-1e30f,-1e30f,-1e30f,-1e30f};
    #pragma unroll
    for (int ct=0;ct<13;ct++){
      float ma = maskadd[ct*16 + l16];
      #pragma unroll
      for (int i=0;i<4;i++){
        float s0 = sc[ct][i]*scale + ma;
        sc[ct][i] = s0;
        mx[i] = fmaxf(mx[i], s0);
      }
    }
    #pragma unroll
    for (int i=0;i<4;i++)
      for (int d=1; d<16; d<<=1) mx[i] = fmaxf(mx[i], __shfl_xor(mx[i], d));
    float sm[4] = {0.f,0.f,0.f,0.f};
    #pragma unroll
    for (int ct=0;ct<13;ct++)
      #pragma unroll
      for (int i=0;i<4;i++){
        float e = __expf(sc[ct][i] - mx[i]);
        sc[ct][i] = e; sm[i] += e;
      }
    #pragma unroll
    for (int i=0;i<4;i++)
      for (int d=1; d<16; d<<=1) sm[i] += __shfl_xor(sm[i], d);
    float rs[4];
    #pragma unroll
    for (int i=0;i<4;i++) rs[i] = 1.f/sm[i];

    #pragma unroll
    for (int ct=0;ct<13;ct++)
      #pragma unroll
      for (int i=0;i<4;i++)
        Pw[(4*g16+i)*232 + ct*16 + l16] = f2b(sc[ct][i]);
    asm volatile("s_waitcnt lgkmcnt(0)" ::: "memory");

    f32x4 cacc[4];
    #pragma unroll
    for (int ni=0;ni<4;ni++) cacc[ni] = zero4();
    #pragma unroll
    for (int kt=0; kt<7; kt++){
      const int ko = kt*32 + 8*g16;
      bf16x8 ap = *(const bf16x8*)&Pw[l16*232 + ko];
      #pragma unroll
      for (int ni=0; ni<4; ni++){
        const int row = ni*16 + l16;
        const int key = ((row>>3)&7) << 3;
        bf16x8 bv8 = *(const bf16x8*)&Vt[row*264 + (ko ^ key)];
        cacc[ni] = __builtin_amdgcn_mfma_f32_16x16x32_bf16(ap, bv8, cacc[ni], 0,0,0);
      }
    }
    #pragma unroll
    for (int ni=0;ni<4;ni++)
      #pragma unroll
      for (int i=0;i<4;i++){
        const int r = rbase + 4*g16 + i;
        if (r < 200)
          ctx[((size_t)(b*200+r))*512 + h*64 + ni*16 + l16] = f2b(cacc[ni][i]*rs[i]);
      }
  }
}

// ------- residual + LayerNorm, bf16 stream (one wave per 512-row) -----------
template<bool RESID, bool F32OUT>
__global__ __launch_bounds__(256) void add_ln_bf(const u16* __restrict__ xin,
    const u16* __restrict__ yin, const float* __restrict__ gam,
    const float* __restrict__ bet, u16* __restrict__ bfout,
    float* __restrict__ fout){
  const int r = blockIdx.x*4 + (threadIdx.x>>6);
  const int lane = threadIdx.x & 63;
  const size_t base = (size_t)r*512 + lane*8;
  uint4 xv = *(const uint4*)&xin[base];
  const u16* xp = (const u16*)&xv;
  float vv[8];
  #pragma unroll
  for (int j=0;j<8;j++) vv[j] = b2f(xp[j]);
  if constexpr (RESID){
    uint4 yv = *(const uint4*)&yin[base];
    const u16* yp = (const u16*)&yv;
    #pragma unroll
    for (int j=0;j<8;j++) vv[j] += b2f(yp[j]);
  }
  float s=0.f, q2=0.f;
  #pragma unroll
  for (int j=0;j<8;j++){ s += vv[j]; q2 += vv[j]*vv[j]; }
  #pragma unroll
  for (int d=1; d<64; d<<=1){ s += __shfl_xor(s,d); q2 += __shfl_xor(q2,d); }
  const float mean = s * (1.f/512.f);
  const float var  = q2 * (1.f/512.f) - mean*mean;
  const float rstd = rsqrtf(var + 1e-5f);
  const int col = lane*8;
  float4 g0 = *(const float4*)&gam[col], g1 = *(const float4*)&gam[col+4];
  float4 b0 = *(const float4*)&bet[col], b1 = *(const float4*)&bet[col+4];
  float gg[8] = {g0.x,g0.y,g0.z,g0.w,g1.x,g1.y,g1.z,g1.w};
  float bb[8] = {b0.x,b0.y,b0.z,b0.w,b1.x,b1.y,b1.z,b1.w};
  float o[8];
  #pragma unroll
  for (int j=0;j<8;j++) o[j] = (vv[j]-mean)*rstd*gg[j] + bb[j];
  if constexpr (F32OUT){
    float4 w0 = {o[0],o[1],o[2],o[3]}, w1 = {o[4],o[5],o[6],o[7]};
    *(float4*)&fout[base] = w0;
    *(float4*)&fout[base+4] = w1;
  } else {
    union { u16 pk[8]; uint4 v; } u;
    #pragma unroll
    for (int j=0;j<8;j++) u.pk[j] = f2b(o[j]);
    *(uint4*)&bfout[base] = u.v;
  }
}

// ---------------------------------------------------------------------------
extern "C" void kernel_launch(void* const* d_in, const int* in_sizes, int n_in,
                              void* d_out, int out_size, void* d_ws, size_t ws_size,
                              hipStream_t stream){
  const float* traj = (const float*)d_in[0];
  const int*   mask = (const int*)  d_in[1];
  const float* pe   = (const float*)d_in[2];
  const float* We   = (const float*)d_in[3];
  const float* be   = (const float*)d_in[4];
  const float* Wq   = (const float*)d_in[5];
  const float* bq   = (const float*)d_in[6];
  const float* Wk   = (const float*)d_in[7];
  const float* bk   = (const float*)d_in[8];
  const float* Wv   = (const float*)d_in[9];
  const float* bv   = (const float*)d_in[10];
  const float* Wo   = (const float*)d_in[11];
  const float* bo   = (const float*)d_in[12];
  const float* ln1g = (const float*)d_in[13];
  const float* ln1b = (const float*)d_in[14];
  const float* W1   = (const float*)d_in[15];
  const float* b1   = (const float*)d_in[16];
  const float* W2   = (const float*)d_in[17];
  const float* b2   = (const float*)d_in[18];
  const float* ln2g = (const float*)d_in[19];
  const float* ln2b = (const float*)d_in[20];
  const float* lnfg = (const float*)d_in[21];
  const float* lnfb = (const float*)d_in[22];

  const size_t PROJ = 512*512, FFW = (size_t)512*2048, TOK = (size_t)25600*512;
  const size_t QKVW = (size_t)1536*512;
  u16* Wcat = (u16*)d_ws;                         // 6 x [1536][512]
  u16* Wot  = Wcat + 6*QKVW;                      // 6 x [512][512]
  u16* W1t  = Wot + 6*PROJ;                       // 6 x [2048][512]
  u16* W2t  = W1t + 6*FFW;                        // 6 x [512][2048]
  u16* xs   = W2t + 6*FFW;                        // bf16 residual stream
  u16* R    = xs + TOK;                           // [25600][2048] scratch
  u16* qkvb = R;                                  // [25600][1536]
  u16* ffb  = R;                                  // [25600][2048]
  u16* cb   = R + (size_t)25600*2048;             // [25600][512] ctx
  u16* yb   = cb + TOK;                           // [25600][512] proj/ff2 out
  float* bcat = (float*)(yb + TOK);               // 6 x [1536]

  dim3 B256(256);
  transpose_k<512,512,(long long)1536*512><<<dim3(16,16,6), B256, 0, stream>>>(Wq, Wcat);
  transpose_k<512,512,(long long)1536*512><<<dim3(16,16,6), B256, 0, stream>>>(Wk, Wcat + 512*512);
  transpose_k<512,512,(long long)1536*512><<<dim3(16,16,6), B256, 0, stream>>>(Wv, Wcat + 1024*512);
  transpose_k<512,512,(long long)512*512> <<<dim3(16,16,6), B256, 0, stream>>>(Wo, Wot);
  transpose_k<512,2048,(long long)512*2048><<<dim3(16,64,6), B256, 0, stream>>>(W1, W1t);
  transpose_k<2048,512,(long long)512*2048><<<dim3(64,16,6), B256, 0, stream>>>(W2, W2t);
  concat_bias<<<36, B256, 0, stream>>>(bq, bk, bv, bcat);

  embed_kernel<<<6400, B256, 0, stream>>>(traj, We, be, pe, xs);

  for (int i=0; i<6; i++){
    gemm256<512,6,false><<<600, 512, 0, stream>>>(xs, Wcat + (size_t)i*QKVW, bcat + i*1536, qkvb, 600);
    attn_kernel<<<1024, B256, 0, stream>>>(qkvb, mask, cb);
    gemm256<512,2,false><<<200, 512, 0, stream>>>(cb, Wot + (size_t)i*PROJ, bo + i*512, yb, 200);
    add_ln_bf<true,false><<<6400, B256, 0, stream>>>(xs, yb, ln1g + i*512, ln1b + i*512, xs, nullptr);
    gemm256<512,8,true><<<800, 512, 0, stream>>>(xs, W1t + (size_t)i*FFW, b1 + i*2048, ffb, 800);
    gemm256<2048,2,false><<<200, 512, 0, stream>>>(ffb, W2t + (size_t)i*FFW, b2 + i*512, yb, 200);
    add_ln_bf<true,false><<<6400, B256, 0, stream>>>(xs, yb, ln2g + i*512, ln2b + i*512, xs, nullptr);
  }
  add_ln_bf<false,true><<<6400, B256, 0, stream>>>(xs, xs, lnfg, lnfb, nullptr, (float*)d_out);
}

// Round 16
// 1612.821 us; speedup vs baseline: 1.1046x; 1.1046x over previous
//
#include <hip/hip_runtime.h>

typedef unsigned short u16;
typedef __bf16 bf16x8 __attribute__((ext_vector_type(8)));
typedef float f32x4 __attribute__((ext_vector_type(4)));

#define DEV __device__ __forceinline__

DEV u16 f2b(float f){
  union { float f; unsigned u; } v; v.f = f;
  unsigned r = v.u + 0x7FFFu + ((v.u >> 16) & 1u);
  return (u16)(r >> 16);
}
DEV float b2f(u16 h){
  union { unsigned u; float f; } v; v.u = ((unsigned)h) << 16; return v.f;
}

DEV f32x4 zero4(){ f32x4 z; z[0]=0.f; z[1]=0.f; z[2]=0.f; z[3]=0.f; return z; }

// async 16B global -> LDS (dest = wave-uniform base + lane*16)
DEV void gload16(const u16* g, const u16* l){
  __builtin_amdgcn_global_load_lds(
      (const __attribute__((address_space(1))) unsigned int*)g,
      (__attribute__((address_space(3))) unsigned int*)l, 16, 0, 0);
}

// ---------------- transpose + fp32->bf16: dst[n*K+k] = bf16(src[k*N+n]) -----
template<int K, int N, long long DSTR>
__global__ __launch_bounds__(256) void transpose_k(const float* __restrict__ src,
                                                   u16* __restrict__ dst){
  __shared__ float tile[32][33];
  const int z = blockIdx.z;
  const float* s = src + (size_t)z*K*N;
  u16* d = dst + (size_t)z*DSTR;
  const int k0 = blockIdx.x*32, n0 = blockIdx.y*32;
  const int tx = threadIdx.x & 31, ty = threadIdx.x >> 5;
  #pragma unroll
  for (int j=0;j<32;j+=8) tile[ty+j][tx] = s[(size_t)(k0+ty+j)*N + n0+tx];
  __syncthreads();
  #pragma unroll
  for (int j=0;j<32;j+=8) d[(size_t)(n0+ty+j)*K + k0+tx] = f2b(tile[tx][ty+j]);
}

// ---------------- bias concat for fused QKV --------------------------------
__global__ __launch_bounds__(256) void concat_bias(const float* __restrict__ bq,
    const float* __restrict__ bk, const float* __restrict__ bv,
    float* __restrict__ bcat){
  int i = blockIdx.x*256 + threadIdx.x;            // over 6*1536
  int l = i / 1536, c = i % 1536;
  float v = (c < 512) ? bq[l*512 + c]
          : (c < 1024) ? bk[l*512 + c - 512]
                       : bv[l*512 + c - 1024];
  bcat[i] = v;
}

// ------- embedding (vectorized 8/thread): x = traj@W_emb + b_emb + pe -------
__global__ __launch_bounds__(256) void embed_kernel(const float* __restrict__ traj,
    const float* __restrict__ We, const float* __restrict__ be,
    const float* __restrict__ pe, u16* __restrict__ xb){
  size_t g = (size_t)blockIdx.x*256 + threadIdx.x;   // over 25600*64 groups
  const int d0 = (int)(g & 63) * 8;
  const size_t tk = g >> 6;
  const float t0 = traj[tk*2], t1 = traj[tk*2+1];
  union { u16 pk[8]; uint4 v; } u;
  #pragma unroll
  for (int j=0;j<8;j++){
    const int d = d0 + j;
    u.pk[j] = f2b(t0*We[d] + t1*We[512+d] + be[d] + pe[200*512 + d]);
  }
  *(uint4*)&xb[tk*512 + d0] = u.v;
}

// ===================== 256x256 8-phase GEMM (T2+T3+T4+T5) ====================
// R13 trunk (best: 1627 us). Hard session constraints:
//  - acc[8][4]=128 regs + ~124 VGPR = 252/wave; 2x252=504<=512 -> 2 waves/SIMD
//    hard cap, 8 VGPR total headroom (R7 disaster; no A-frag dbuf possible).
//  - ceil(tiles/256)*T makespan is a hard LB; grid games can't beat it (R10).
//  - fine 8-phase interleave required; merging phases regresses (R4 == m196).
//  - trailing barrier only at P4/P8 (publication points); others redundant (R13).
template<int K, int NTI, bool RELU>
__global__ __launch_bounds__(512, 2) void gemm256(const u16* __restrict__ A,
    const u16* __restrict__ Bt, const float* __restrict__ bias,
    u16* __restrict__ outp, int nwg){
  constexpr int N = NTI*256;
  constexpr int NT = K/64;              // K-tiles (even for K=512/2048)
  __shared__ __align__(16) u16 S[65536];
  const int t = threadIdx.x, lane = t&63, w = t>>6;
  const int l16 = lane&15, g16 = lane>>4;
  const int wm = w>>2, wn = w&3;

  // bijective XCD swizzle (m204)
  const int orig = blockIdx.x;
  const int qq = nwg>>3, rr = nwg&7, xc = orig&7, oo = orig>>3;
  const int wg = (xc<rr ? xc*(qq+1) : rr*(qq+1)+(xc-rr)*qq) + oo;
  const int mt = wg / NTI, ntl = wg % NTI;
  const size_t m0 = (size_t)mt*256, n0 = (size_t)ntl*256;
  const u16* Ab = A + m0*K;
  const u16* Bb = Bt + n0*K;

  const int srow = t>>3;
  const int scol = 8*((t&7) ^ ((t>>3)&7));
  const int kx = (l16&7)<<3;            // read-side XOR (u16 units)

  // precomputed staging source pointers (rows srow, 64+srow, 128+srow, 192+srow)
  const u16* gA[4] = {Ab + (size_t)srow*K + scol,       Ab + (size_t)(64+srow)*K + scol,
                      Ab + (size_t)(128+srow)*K + scol, Ab + (size_t)(192+srow)*K + scol};
  const u16* gB[4] = {Bb + (size_t)srow*K + scol,       Bb + (size_t)(64+srow)*K + scol,
                      Bb + (size_t)(128+srow)*K + scol, Bb + (size_t)(192+srow)*K + scol};

  f32x4 acc[8][4];
  #pragma unroll
  for (int i=0;i<8;i++)
    #pragma unroll
    for (int j=0;j<4;j++) acc[i][j] = zero4();

  #define STG(gp, kb, region, half)                                         \
    { gload16(gp[2*(half)]   + (kb), &S[(region) + (half)*8192 + w*512]);   \
      gload16(gp[2*(half)+1] + (kb), &S[(region) + (half)*8192 + 4096 + w*512]); }

  // prologue: tile0 A+B (buf0), tile1 B (buf1.B); tile1 A comes in P1/P2
  STG(gA, 0, 0, 0);      STG(gA, 0, 0, 1);
  STG(gB, 0, 16384, 0);  STG(gB, 0, 16384, 1);
  STG(gB, 64, 49152, 0); STG(gB, 64, 49152, 1);
  asm volatile("s_waitcnt vmcnt(4)" ::: "memory");   // buf0 landed; b1.B in flight
  __builtin_amdgcn_s_barrier();

  bf16x8 breg[4][2];

  // ENDBAR: trailing barrier only where staged data is published (P4/P8)
  #define PHASE(AB, BB, Q, LOADB, STG_STMT, VMW, ENDBAR)                    \
  {                                                                         \
    bf16x8 af[2][2];                                                        \
    _Pragma("unroll")                                                       \
    for (int ks=0;ks<2;ks++){                                               \
      _Pragma("unroll")                                                     \
      for (int j=0;j<2;j++)                                                 \
        af[j][ks] = *(const bf16x8*)&S[(AB) + (wm*128 + (2*(Q)+j)*16 + l16)*64 \
                                        + ((ks*32 + g16*8) ^ kx)];          \
      if (LOADB){                                                           \
        _Pragma("unroll")                                                   \
        for (int ni=0;ni<4;ni++)                                            \
          breg[ni][ks] = *(const bf16x8*)&S[(BB) + (wn*64 + ni*16 + l16)*64 \
                                             + ((ks*32 + g16*8) ^ kx)];     \
      }                                                                     \
    }                                                                       \
    STG_STMT;                                                               \
    __builtin_amdgcn_s_barrier();                                           \
    __builtin_amdgcn_s_setprio(1);                                          \
    _Pragma("unroll")                                                       \
    for (int ks=0;ks<2;ks++){                                               \
      _Pragma("unroll")                                                     \
      for (int j=0;j<2;j++){                                                \
        _Pragma("unroll")                                                   \
        for (int ni=0;ni<4;ni++)                                            \
          acc[2*(Q)+j][ni] = __builtin_amdgcn_mfma_f32_16x16x32_bf16(       \
              af[j][ks], breg[ni][ks], acc[2*(Q)+j][ni], 0, 0, 0);          \
      }                                                                     \
    }                                                                       \
    __builtin_amdgcn_s_setprio(0);                                          \
    VMW;                                                                    \
    if (ENDBAR) __builtin_amdgcn_s_barrier();                               \
  }

  for (int it=0; it<NT/2; ++it){
    const bool last = (it == NT/2 - 1);
    const int k1 = 2*it+1, k2 = 2*it+2, k3 = 2*it+3;   // k2,k3 used iff !last
    // P1-P4: tile 2t from buf0; stage k1.A (->b1.A), k2.B (->b0.B)
    PHASE(0,     16384, 0, true,  STG(gA, k1*64, 32768, 0), ((void)0), 0);
    PHASE(0,     16384, 1, false, STG(gA, k1*64, 32768, 1), ((void)0), 0);
    PHASE(0,     16384, 2, false, if(!last){ STG(gB, k2*64, 16384, 0) }, ((void)0), 0);
    PHASE(0,     16384, 3, false, if(!last){ STG(gB, k2*64, 16384, 1) },
          if(last){ asm volatile("s_waitcnt vmcnt(0)" ::: "memory"); }
          else    { asm volatile("s_waitcnt vmcnt(4)" ::: "memory"); }, 1);
    // P5-P8: tile 2t+1 from buf1; stage k2.A (->b0.A), k3.B (->b1.B)
    PHASE(32768, 49152, 0, true,  if(!last){ STG(gA, k2*64, 0, 0) }, ((void)0), 0);
    PHASE(32768, 49152, 1, false, if(!last){ STG(gA, k2*64, 0, 1) }, ((void)0), 0);
    PHASE(32768, 49152, 2, false, if(!last){ STG(gB, k3*64, 49152, 0) }, ((void)0), 0);
    PHASE(32768, 49152, 3, false, if(!last){ STG(gB, k3*64, 49152, 1) },
          if(!last){ asm volatile("s_waitcnt vmcnt(4)" ::: "memory"); }, 1);
  }
  #undef PHASE
  #undef STG

  // -------- coalesced bf16 epilogue via LDS, 2 passes (4 barriers total) ----
  __syncthreads();
  float bs[4];
  #pragma unroll
  for (int ni=0;ni<4;ni++) bs[ni] = bias[n0 + wn*64 + ni*16 + l16];
  constexpr int LDE = 264;                           // 256 + 8 pad (u16)
  #pragma unroll
  for (int pass=0; pass<2; ++pass){
    const int miB = pass*4;
    #pragma unroll
    for (int miL=0; miL<4; miL++){
      #pragma unroll
      for (int ni=0;ni<4;ni++){
        #pragma unroll
        for (int i=0;i<4;i++){
          float vv = acc[miB+miL][ni][i] + bs[ni];
          if constexpr (RELU) vv = fmaxf(vv, 0.f);
          S[(wm*64 + miL*16 + 4*g16 + i)*LDE + wn*64 + ni*16 + l16] = f2b(vv);
        }
      }
    }
    __syncthreads();
    #pragma unroll
    for (int cc=0; cc<8; cc++){
      const int c = t + cc*512;            // 0..4095 (128 rows x 32 chunks)
      const int R = c >> 5, ck = c & 31;   // R: wmR*64 + miL*16 + r
      uint4 v = *(const uint4*)&S[R*LDE + ck*8];
      const size_t grow = m0 + (size_t)(R>>6)*128 + miB*16 + (R&63);
      *(uint4*)&outp[grow*N + n0 + ck*8] = v;
    }
    if (pass == 0) __syncthreads();
  }
}

// ---------------- attention: one block per (b,h) ----------------------------
// R13 version (116 VGPR, 4 waves/SIMD). R14 lesson: the Vt anti-conflict
// swizzle cut SQ_LDS_BANK_CONFLICT 4.7e6->1.9e6 but cost +16 VGPR -> 3
// waves/SIMD, and this kernel is latency-bound (global K/Q reads feed MFMA
// directly) -- occupancy beats bank conflicts here. Do not re-add.
__global__ __launch_bounds__(256) void attn_kernel(const u16* __restrict__ qkv,
    const int* __restrict__ mask, u16* __restrict__ ctx){
  __shared__ __align__(16) u16 Vt[64*232];        // V^T, zero-padded s>=200
  __shared__ __align__(16) u16 Ps[4*16*232];      // per-wave P tiles
  __shared__ float maskadd[208];
  const int bh = blockIdx.x, b = bh>>3, h = bh&7;
  const int t = threadIdx.x, lane = t&63, w = t>>6;
  const int g16 = lane>>4, l16 = lane&15;

  for (int i=t; i<1856; i+=256) ((uint4*)Vt)[i] = make_uint4(0,0,0,0);
  for (int i=t; i<1856; i+=256) ((uint4*)Ps)[i] = make_uint4(0,0,0,0);
  __syncthreads();

  // stage V^T: coalesced 16B row loads, scatter-transpose into LDS
  for (int idx = t; idx < 1600; idx += 256){
    const int s = idx >> 3, d0 = (idx & 7) * 8;
    uint4 v4 = *(const uint4*)&qkv[((size_t)(b*200+s))*1536 + 1024 + h*64 + d0];
    const u16* e = (const u16*)&v4;
    #pragma unroll
    for (int j=0;j<8;j++) Vt[(d0+j)*232 + s] = e[j];
  }
  if (t < 208) maskadd[t] = (t < 200 && mask[b*200+t] != 0) ? 0.f : -1e30f;
  __syncthreads();

  u16* Pw = Ps + w*16*232;
  const float scale = 0.125f;   // 1/sqrt(64)

  for (int rt = w; rt < 13; rt += 4){
    const int rbase = rt*16;
    f32x4 sc[13];
    #pragma unroll
    for (int ct=0;ct<13;ct++) sc[ct] = zero4();

    #pragma unroll
    for (int ks=0; ks<64; ks+=32){
      const int ko = ks + 8*g16;
      const size_t qrow = (size_t)(b*200) + rbase + l16;
      bf16x8 aq = *(const bf16x8*)&qkv[qrow*1536 + h*64 + ko];
      #pragma unroll
      for (int ct=0; ct<13; ct++){
        const size_t krow = (size_t)(b*200) + ct*16 + l16;
        bf16x8 bk8 = *(const bf16x8*)&qkv[krow*1536 + 512 + h*64 + ko];
        sc[ct] = __builtin_amdgcn_mfma_f32_16x16x32_bf16(aq, bk8, sc[ct], 0,0,0);
      }
    }

    float mx[4] = {-1e30f,-1e30f,-1e30f,-1e30f};
    #pragma unroll
    for (int ct=0;ct<13;ct++){
      float ma = maskadd[ct*16 + l16];
      #pragma unroll
      for (int i=0;i<4;i++){
        float s0 = sc[ct][i]*scale + ma;
        sc[ct][i] = s0;
        mx[i] = fmaxf(mx[i], s0);
      }
    }
    #pragma unroll
    for (int i=0;i<4;i++)
      for (int d=1; d<16; d<<=1) mx[i] = fmaxf(mx[i], __shfl_xor(mx[i], d));
    float sm[4] = {0.f,0.f,0.f,0.f};
    #pragma unroll
    for (int ct=0;ct<13;ct++)
      #pragma unroll
      for (int i=0;i<4;i++){
        float e = __expf(sc[ct][i] - mx[i]);
        sc[ct][i] = e; sm[i] += e;
      }
    #pragma unroll
    for (int i=0;i<4;i++)
      for (int d=1; d<16; d<<=1) sm[i] += __shfl_xor(sm[i], d);
    float rs[4];
    #pragma unroll
    for (int i=0;i<4;i++) rs[i] = 1.f/sm[i];

    #pragma unroll
    for (int ct=0;ct<13;ct++)
      #pragma unroll
      for (int i=0;i<4;i++)
        Pw[(4*g16+i)*232 + ct*16 + l16] = f2b(sc[ct][i]);
    asm volatile("s_waitcnt lgkmcnt(0)" ::: "memory");

    f32x4 cacc[4];
    #pragma unroll
    for (int ni=0;ni<4;ni++) cacc[ni] = zero4();
    #pragma unroll
    for (int kt=0; kt<7; kt++){
      const int ko = kt*32 + 8*g16;
      bf16x8 ap = *(const bf16x8*)&Pw[l16*232 + ko];
      #pragma unroll
      for (int ni=0; ni<4; ni++){
        bf16x8 bv8 = *(const bf16x8*)&Vt[(ni*16 + l16)*232 + ko];
        cacc[ni] = __builtin_amdgcn_mfma_f32_16x16x32_bf16(ap, bv8, cacc[ni], 0,0,0);
      }
    }
    #pragma unroll
    for (int ni=0;ni<4;ni++)
      #pragma unroll
      for (int i=0;i<4;i++){
        const int r = rbase + 4*g16 + i;
        if (r < 200)
          ctx[((size_t)(b*200+r))*512 + h*64 + ni*16 + l16] = f2b(cacc[ni][i]*rs[i]);
      }
  }
}

// ------- residual + LayerNorm, bf16 stream (one wave per 512-row) -----------
template<bool RESID, bool F32OUT>
__global__ __launch_bounds__(256) void add_ln_bf(const u16* __restrict__ xin,
    const u16* __restrict__ yin, const float* __restrict__ gam,
    const float* __restrict__ bet, u16* __restrict__ bfout,
    float* __restrict__ fout){
  const int r = blockIdx.x*4 + (threadIdx.x>>6);
  const int lane = threadIdx.x & 63;
  const size_t base = (size_t)r*512 + lane*8;
  uint4 xv = *(const uint4*)&xin[base];
  const u16* xp = (const u16*)&xv;
  float vv[8];
  #pragma unroll
  for (int j=0;j<8;j++) vv[j] = b2f(xp[j]);
  if constexpr (RESID){
    uint4 yv = *(const uint4*)&yin[base];
    const u16* yp = (const u16*)&yv;
    #pragma unroll
    for (int j=0;j<8;j++) vv[j] += b2f(yp[j]);
  }
  float s=0.f, q2=0.f;
  #pragma unroll
  for (int j=0;j<8;j++){ s += vv[j]; q2 += vv[j]*vv[j]; }
  #pragma unroll
  for (int d=1; d<64; d<<=1){ s += __shfl_xor(s,d); q2 += __shfl_xor(q2,d); }
  const float mean = s * (1.f/512.f);
  const float var  = q2 * (1.f/512.f) - mean*mean;
  const float rstd = rsqrtf(var + 1e-5f);
  const int col = lane*8;
  float4 g0 = *(const float4*)&gam[col], g1 = *(const float4*)&gam[col+4];
  float4 b0 = *(const float4*)&bet[col], b1 = *(const float4*)&bet[col+4];
  float gg[8] = {g0.x,g0.y,g0.z,g0.w,g1.x,g1.y,g1.z,g1.w};
  float bb[8] = {b0.x,b0.y,b0.z,b0.w,b1.x,b1.y,b1.z,b1.w};
  float o[8];
  #pragma unroll
  for (int j=0;j<8;j++) o[j] = (vv[j]-mean)*rstd*gg[j] + bb[j];
  if constexpr (F32OUT){
    float4 w0 = {o[0],o[1],o[2],o[3]}, w1 = {o[4],o[5],o[6],o[7]};
    *(float4*)&fout[base] = w0;
    *(float4*)&fout[base+4] = w1;
  } else {
    union { u16 pk[8]; uint4 v; } u;
    #pragma unroll
    for (int j=0;j<8;j++) u.pk[j] = f2b(o[j]);
    *(uint4*)&bfout[base] = u.v;
  }
}

// ---------------------------------------------------------------------------
extern "C" void kernel_launch(void* const* d_in, const int* in_sizes, int n_in,
                              void* d_out, int out_size, void* d_ws, size_t ws_size,
                              hipStream_t stream){
  const float* traj = (const float*)d_in[0];
  const int*   mask = (const int*)  d_in[1];
  const float* pe   = (const float*)d_in[2];
  const float* We   = (const float*)d_in[3];
  const float* be   = (const float*)d_in[4];
  const float* Wq   = (const float*)d_in[5];
  const float* bq   = (const float*)d_in[6];
  const float* Wk   = (const float*)d_in[7];
  const float* bk   = (const float*)d_in[8];
  const float* Wv   = (const float*)d_in[9];
  const float* bv   = (const float*)d_in[10];
  const float* Wo   = (const float*)d_in[11];
  const float* bo   = (const float*)d_in[12];
  const float* ln1g = (const float*)d_in[13];
  const float* ln1b = (const float*)d_in[14];
  const float* W1   = (const float*)d_in[15];
  const float* b1   = (const float*)d_in[16];
  const float* W2   = (const float*)d_in[17];
  const float* b2   = (const float*)d_in[18];
  const float* ln2g = (const float*)d_in[19];
  const float* ln2b = (const float*)d_in[20];
  const float* lnfg = (const float*)d_in[21];
  const float* lnfb = (const float*)d_in[22];

  const size_t PROJ = 512*512, FFW = (size_t)512*2048, TOK = (size_t)25600*512;
  const size_t QKVW = (size_t)1536*512;
  u16* Wcat = (u16*)d_ws;                         // 6 x [1536][512]
  u16* Wot  = Wcat + 6*QKVW;                      // 6 x [512][512]
  u16* W1t  = Wot + 6*PROJ;                       // 6 x [2048][512]
  u16* W2t  = W1t + 6*FFW;                        // 6 x [512][2048]
  u16* xs   = W2t + 6*FFW;                        // bf16 residual stream
  u16* R    = xs + TOK;                           // [25600][2048] scratch
  u16* qkvb = R;                                  // [25600][1536]
  u16* ffb  = R;                                  // [25600][2048]
  u16* cb   = R + (size_t)25600*2048;             // [25600][512] ctx
  u16* yb   = cb + TOK;                           // [25600][512] proj/ff2 out
  float* bcat = (float*)(yb + TOK);               // 6 x [1536]

  dim3 B256(256);
  transpose_k<512,512,(long long)1536*512><<<dim3(16,16,6), B256, 0, stream>>>(Wq, Wcat);
  transpose_k<512,512,(long long)1536*512><<<dim3(16,16,6), B256, 0, stream>>>(Wk, Wcat + 512*512);
  transpose_k<512,512,(long long)1536*512><<<dim3(16,16,6), B256, 0, stream>>>(Wv, Wcat + 1024*512);
  transpose_k<512,512,(long long)512*512> <<<dim3(16,16,6), B256, 0, stream>>>(Wo, Wot);
  transpose_k<512,2048,(long long)512*2048><<<dim3(16,64,6), B256, 0, stream>>>(W1, W1t);
  transpose_k<2048,512,(long long)512*2048><<<dim3(64,16,6), B256, 0, stream>>>(W2, W2t);
  concat_bias<<<36, B256, 0, stream>>>(bq, bk, bv, bcat);

  embed_kernel<<<6400, B256, 0, stream>>>(traj, We, be, pe, xs);

  for (int i=0; i<6; i++){
    gemm256<512,6,false><<<600, 512, 0, stream>>>(xs, Wcat + (size_t)i*QKVW, bcat + i*1536, qkvb, 600);
    attn_kernel<<<1024, B256, 0, stream>>>(qkvb, mask, cb);
    gemm256<512,2,false><<<200, 512, 0, stream>>>(cb, Wot + (size_t)i*PROJ, bo + i*512, yb, 200);
    add_ln_bf<true,false><<<6400, B256, 0, stream>>>(xs, yb, ln1g + i*512, ln1b + i*512, xs, nullptr);
    gemm256<512,8,true><<<800, 512, 0, stream>>>(xs, W1t + (size_t)i*FFW, b1 + i*2048, ffb, 800);
    gemm256<2048,2,false><<<200, 512, 0, stream>>>(ffb, W2t + (size_t)i*FFW, b2 + i*512, yb, 200);
    add_ln_bf<true,false><<<6400, B256, 0, stream>>>(xs, yb, ln2g + i*512, ln2b + i*512, xs, nullptr);
  }
  add_ln_bf<false,true><<<6400, B256, 0, stream>>>(xs, xs, lnfg, lnfb, nullptr, (float*)d_out);
}

// Round 17
// 1604.272 us; speedup vs baseline: 1.1104x; 1.0053x over previous
//
#include <hip/hip_runtime.h>

typedef unsigned short u16;
typedef __bf16 bf16x8 __attribute__((ext_vector_type(8)));
typedef float f32x4 __attribute__((ext_vector_type(4)));

#define DEV __device__ __forceinline__

DEV u16 f2b(float f){
  union { float f; unsigned u; } v; v.f = f;
  unsigned r = v.u + 0x7FFFu + ((v.u >> 16) & 1u);
  return (u16)(r >> 16);
}
DEV float b2f(u16 h){
  union { unsigned u; float f; } v; v.u = ((unsigned)h) << 16; return v.f;
}

DEV f32x4 zero4(){ f32x4 z; z[0]=0.f; z[1]=0.f; z[2]=0.f; z[3]=0.f; return z; }

// async 16B global -> LDS (dest = wave-uniform base + lane*16)
DEV void gload16(const u16* g, const u16* l){
  __builtin_amdgcn_global_load_lds(
      (const __attribute__((address_space(1))) unsigned int*)g,
      (__attribute__((address_space(3))) unsigned int*)l, 16, 0, 0);
}

// ---------------- transpose + fp32->bf16: dst[n*K+k] = bf16(src[k*N+n]) -----
template<int K, int N, long long DSTR>
__global__ __launch_bounds__(256) void transpose_k(const float* __restrict__ src,
                                                   u16* __restrict__ dst){
  __shared__ float tile[32][33];
  const int z = blockIdx.z;
  const float* s = src + (size_t)z*K*N;
  u16* d = dst + (size_t)z*DSTR;
  const int k0 = blockIdx.x*32, n0 = blockIdx.y*32;
  const int tx = threadIdx.x & 31, ty = threadIdx.x >> 5;
  #pragma unroll
  for (int j=0;j<32;j+=8) tile[ty+j][tx] = s[(size_t)(k0+ty+j)*N + n0+tx];
  __syncthreads();
  #pragma unroll
  for (int j=0;j<32;j+=8) d[(size_t)(n0+ty+j)*K + k0+tx] = f2b(tile[tx][ty+j]);
}

// ---------------- bias concat for fused QKV --------------------------------
__global__ __launch_bounds__(256) void concat_bias(const float* __restrict__ bq,
    const float* __restrict__ bk, const float* __restrict__ bv,
    float* __restrict__ bcat){
  int i = blockIdx.x*256 + threadIdx.x;            // over 6*1536
  int l = i / 1536, c = i % 1536;
  float v = (c < 512) ? bq[l*512 + c]
          : (c < 1024) ? bk[l*512 + c - 512]
                       : bv[l*512 + c - 1024];
  bcat[i] = v;
}

// ------- embedding (vectorized 8/thread): x = traj@W_emb + b_emb + pe -------
__global__ __launch_bounds__(256) void embed_kernel(const float* __restrict__ traj,
    const float* __restrict__ We, const float* __restrict__ be,
    const float* __restrict__ pe, u16* __restrict__ xb){
  size_t g = (size_t)blockIdx.x*256 + threadIdx.x;   // over 25600*64 groups
  const int d0 = (int)(g & 63) * 8;
  const size_t tk = g >> 6;
  const float t0 = traj[tk*2], t1 = traj[tk*2+1];
  union { u16 pk[8]; uint4 v; } u;
  #pragma unroll
  for (int j=0;j<8;j++){
    const int d = d0 + j;
    u.pk[j] = f2b(t0*We[d] + t1*We[512+d] + be[d] + pe[200*512 + d]);
  }
  *(uint4*)&xb[tk*512 + d0] = u.v;
}

// ===================== 256x256 8-phase GEMM (T2+T3+T4+T5) ====================
// R13 trunk. Used for Wo and FF2 (no quantization benefit from smaller tile).
template<int K, int NTI, bool RELU>
__global__ __launch_bounds__(512, 2) void gemm256(const u16* __restrict__ A,
    const u16* __restrict__ Bt, const float* __restrict__ bias,
    u16* __restrict__ outp, int nwg){
  constexpr int N = NTI*256;
  constexpr int NT = K/64;              // K-tiles (even for K=512/2048)
  __shared__ __align__(16) u16 S[65536];
  const int t = threadIdx.x, lane = t&63, w = t>>6;
  const int l16 = lane&15, g16 = lane>>4;
  const int wm = w>>2, wn = w&3;

  // bijective XCD swizzle (m204)
  const int orig = blockIdx.x;
  const int qq = nwg>>3, rr = nwg&7, xc = orig&7, oo = orig>>3;
  const int wg = (xc<rr ? xc*(qq+1) : rr*(qq+1)+(xc-rr)*qq) + oo;
  const int mt = wg / NTI, ntl = wg % NTI;
  const size_t m0 = (size_t)mt*256, n0 = (size_t)ntl*256;
  const u16* Ab = A + m0*K;
  const u16* Bb = Bt + n0*K;

  const int srow = t>>3;
  const int scol = 8*((t&7) ^ ((t>>3)&7));
  const int kx = (l16&7)<<3;            // read-side XOR (u16 units)

  const u16* gA[4] = {Ab + (size_t)srow*K + scol,       Ab + (size_t)(64+srow)*K + scol,
                      Ab + (size_t)(128+srow)*K + scol, Ab + (size_t)(192+srow)*K + scol};
  const u16* gB[4] = {Bb + (size_t)srow*K + scol,       Bb + (size_t)(64+srow)*K + scol,
                      Bb + (size_t)(128+srow)*K + scol, Bb + (size_t)(192+srow)*K + scol};

  f32x4 acc[8][4];
  #pragma unroll
  for (int i=0;i<8;i++)
    #pragma unroll
    for (int j=0;j<4;j++) acc[i][j] = zero4();

  #define STG(gp, kb, region, half)                                         \
    { gload16(gp[2*(half)]   + (kb), &S[(region) + (half)*8192 + w*512]);   \
      gload16(gp[2*(half)+1] + (kb), &S[(region) + (half)*8192 + 4096 + w*512]); }

  STG(gA, 0, 0, 0);      STG(gA, 0, 0, 1);
  STG(gB, 0, 16384, 0);  STG(gB, 0, 16384, 1);
  STG(gB, 64, 49152, 0); STG(gB, 64, 49152, 1);
  asm volatile("s_waitcnt vmcnt(4)" ::: "memory");
  __builtin_amdgcn_s_barrier();

  bf16x8 breg[4][2];

  #define PHASE(AB, BB, Q, LOADB, STG_STMT, VMW, ENDBAR)                    \
  {                                                                         \
    bf16x8 af[2][2];                                                        \
    _Pragma("unroll")                                                       \
    for (int ks=0;ks<2;ks++){                                               \
      _Pragma("unroll")                                                     \
      for (int j=0;j<2;j++)                                                 \
        af[j][ks] = *(const bf16x8*)&S[(AB) + (wm*128 + (2*(Q)+j)*16 + l16)*64 \
                                        + ((ks*32 + g16*8) ^ kx)];          \
      if (LOADB){                                                           \
        _Pragma("unroll")                                                   \
        for (int ni=0;ni<4;ni++)                                            \
          breg[ni][ks] = *(const bf16x8*)&S[(BB) + (wn*64 + ni*16 + l16)*64 \
                                             + ((ks*32 + g16*8) ^ kx)];     \
      }                                                                     \
    }                                                                       \
    STG_STMT;                                                               \
    __builtin_amdgcn_s_barrier();                                           \
    __builtin_amdgcn_s_setprio(1);                                          \
    _Pragma("unroll")                                                       \
    for (int ks=0;ks<2;ks++){                                               \
      _Pragma("unroll")                                                     \
      for (int j=0;j<2;j++){                                                \
        _Pragma("unroll")                                                   \
        for (int ni=0;ni<4;ni++)                                            \
          acc[2*(Q)+j][ni] = __builtin_amdgcn_mfma_f32_16x16x32_bf16(       \
              af[j][ks], breg[ni][ks], acc[2*(Q)+j][ni], 0, 0, 0);          \
      }                                                                     \
    }                                                                       \
    __builtin_amdgcn_s_setprio(0);                                          \
    VMW;                                                                    \
    if (ENDBAR) __builtin_amdgcn_s_barrier();                               \
  }

  for (int it=0; it<NT/2; ++it){
    const bool last = (it == NT/2 - 1);
    const int k1 = 2*it+1, k2 = 2*it+2, k3 = 2*it+3;   // k2,k3 used iff !last
    PHASE(0,     16384, 0, true,  STG(gA, k1*64, 32768, 0), ((void)0), 0);
    PHASE(0,     16384, 1, false, STG(gA, k1*64, 32768, 1), ((void)0), 0);
    PHASE(0,     16384, 2, false, if(!last){ STG(gB, k2*64, 16384, 0) }, ((void)0), 0);
    PHASE(0,     16384, 3, false, if(!last){ STG(gB, k2*64, 16384, 1) },
          if(last){ asm volatile("s_waitcnt vmcnt(0)" ::: "memory"); }
          else    { asm volatile("s_waitcnt vmcnt(4)" ::: "memory"); }, 1);
    PHASE(32768, 49152, 0, true,  if(!last){ STG(gA, k2*64, 0, 0) }, ((void)0), 0);
    PHASE(32768, 49152, 1, false, if(!last){ STG(gA, k2*64, 0, 1) }, ((void)0), 0);
    PHASE(32768, 49152, 2, false, if(!last){ STG(gB, k3*64, 49152, 0) }, ((void)0), 0);
    PHASE(32768, 49152, 3, false, if(!last){ STG(gB, k3*64, 49152, 1) },
          if(!last){ asm volatile("s_waitcnt vmcnt(4)" ::: "memory"); }, 1);
  }
  #undef PHASE
  #undef STG

  __syncthreads();
  float bs[4];
  #pragma unroll
  for (int ni=0;ni<4;ni++) bs[ni] = bias[n0 + wn*64 + ni*16 + l16];
  constexpr int LDE = 264;                           // 256 + 8 pad (u16)
  #pragma unroll
  for (int pass=0; pass<2; ++pass){
    const int miB = pass*4;
    #pragma unroll
    for (int miL=0; miL<4; miL++){
      #pragma unroll
      for (int ni=0;ni<4;ni++){
        #pragma unroll
        for (int i=0;i<4;i++){
          float vv = acc[miB+miL][ni][i] + bs[ni];
          if constexpr (RELU) vv = fmaxf(vv, 0.f);
          S[(wm*64 + miL*16 + 4*g16 + i)*LDE + wn*64 + ni*16 + l16] = f2b(vv);
        }
      }
    }
    __syncthreads();
    #pragma unroll
    for (int cc=0; cc<8; cc++){
      const int c = t + cc*512;
      const int R = c >> 5, ck = c & 31;
      uint4 v = *(const uint4*)&S[R*LDE + ck*8];
      const size_t grow = m0 + (size_t)(R>>6)*128 + miB*16 + (R&63);
      *(uint4*)&outp[grow*N + n0 + ck*8] = v;
    }
    if (pass == 0) __syncthreads();
  }
}

// ===================== 128x256 2-phase GEMM (half-T tile) ====================
// R16: same verified phase texture (16 MFMA/barrier-pair, swizzle pair with
// row&7 == l16&7 invariant, R13 minimal barriers), 3-slot rotating buffers
// (stage tile m+2 during tile m; slot (m+2)%3 was last read at tile m-1 and
// freed by endbar(m-1) -> barrier-distance rule satisfied), counted vmcnt(6),
// R8-style tail peel. Used for QKV (1200 tiles -> 2.5T) and FF1 (1600 -> 3.5T)
// where the 256^2 tile wastes 0.66T/0.87T of makespan quantization.
// LDS: A slots 3x8192 u16 @0, B slots 3x16384 u16 @24576 -> 73728 u16 = 144KB.
template<int K, int NTI, bool RELU>
__global__ __launch_bounds__(512, 2) void gemm128(const u16* __restrict__ A,
    const u16* __restrict__ Bt, const float* __restrict__ bias,
    u16* __restrict__ outp, int nwg){
  constexpr int N = NTI*256;
  constexpr int NT = K/64;
  __shared__ __align__(16) u16 S[73728];
  const int t = threadIdx.x, lane = t&63, w = t>>6;
  const int l16 = lane&15, g16 = lane>>4;
  const int wm = w>>2, wn = w&3;            // wm in [0,2): 64 rows; wn in [0,4): 64 cols

  // bijective XCD swizzle (m204); nwg % 8 == 0 for all uses
  const int orig = blockIdx.x;
  const int qq = nwg>>3, rr = nwg&7, xc = orig&7, oo = orig>>3;
  const int wg = (xc<rr ? xc*(qq+1) : rr*(qq+1)+(xc-rr)*qq) + oo;
  const int mt = wg / NTI, ntl = wg % NTI;
  const size_t m0 = (size_t)mt*128, n0 = (size_t)ntl*256;
  const u16* Ab = A + m0*K;
  const u16* Bb = Bt + n0*K;

  const int srow = t>>3;                    // 0..63
  const int scol = 8*((t&7) ^ ((t>>3)&7));  // inverse-swizzled source chunk
  const int kx = (l16&7)<<3;                // read-side XOR (u16 units)

  const u16* gA[2] = {Ab + (size_t)srow*K + scol, Ab + (size_t)(64+srow)*K + scol};
  const u16* gB[4] = {Bb + (size_t)srow*K + scol,       Bb + (size_t)(64+srow)*K + scol,
                      Bb + (size_t)(128+srow)*K + scol, Bb + (size_t)(192+srow)*K + scol};

  f32x4 acc[4][4];
  #pragma unroll
  for (int i=0;i<4;i++)
    #pragma unroll
    for (int j=0;j<4;j++) acc[i][j] = zero4();

  // one line = 64 rows x 64 u16 = 4096 u16 (512 thr x 16B)
  #define SGA(kt, sl, li) gload16(gA[li] + (kt)*64, &S[(sl)*8192 + (li)*4096 + w*512])
  #define SGB(kt, sl, li) gload16(gB[li] + (kt)*64, &S[24576 + (sl)*16384 + (li)*4096 + w*512])

  // prologue: tile0 -> slot0, tile1 -> slot1 (6 ops each)
  SGA(0,0,0); SGA(0,0,1); SGB(0,0,0); SGB(0,0,1); SGB(0,0,2); SGB(0,0,3);
  SGA(1,1,0); SGA(1,1,1); SGB(1,1,0); SGB(1,1,1); SGB(1,1,2); SGB(1,1,3);
  asm volatile("s_waitcnt vmcnt(6)" ::: "memory");   // tile0 landed; tile1 in flight
  __builtin_amdgcn_s_barrier();

  bf16x8 breg[4][2];

  for (int m=0; m<NT; ++m){
    const int cs = m % 3, ss = (m+2) % 3;
    const int sA = cs*8192, sB = 24576 + cs*16384;
    const bool stg = (m+2 < NT);
    const int k2 = m+2;
    // ---- P1: A-frags mi 0,1 + all B-frags; stage k2 {A0,A1,B0}
    {
      bf16x8 af[2][2];
      #pragma unroll
      for (int ks=0;ks<2;ks++){
        #pragma unroll
        for (int j=0;j<2;j++)
          af[j][ks] = *(const bf16x8*)&S[sA + (wm*64 + j*16 + l16)*64
                                          + ((ks*32 + g16*8) ^ kx)];
        #pragma unroll
        for (int ni=0;ni<4;ni++)
          breg[ni][ks] = *(const bf16x8*)&S[sB + (wn*64 + ni*16 + l16)*64
                                             + ((ks*32 + g16*8) ^ kx)];
      }
      if (stg){ SGA(k2,ss,0); SGA(k2,ss,1); SGB(k2,ss,0); }
      __builtin_amdgcn_s_barrier();
      __builtin_amdgcn_s_setprio(1);
      #pragma unroll
      for (int ks=0;ks<2;ks++)
        #pragma unroll
        for (int j=0;j<2;j++)
          #pragma unroll
          for (int ni=0;ni<4;ni++)
            acc[j][ni] = __builtin_amdgcn_mfma_f32_16x16x32_bf16(
                af[j][ks], breg[ni][ks], acc[j][ni], 0, 0, 0);
      __builtin_amdgcn_s_setprio(0);
    }
    // ---- P2: A-frags mi 2,3; stage k2 {B1,B2,B3}; counted vmcnt; endbar
    {
      bf16x8 af[2][2];
      #pragma unroll
      for (int ks=0;ks<2;ks++)
        #pragma unroll
        for (int j=0;j<2;j++)
          af[j][ks] = *(const bf16x8*)&S[sA + (wm*64 + (2+j)*16 + l16)*64
                                          + ((ks*32 + g16*8) ^ kx)];
      if (stg){ SGB(k2,ss,1); SGB(k2,ss,2); SGB(k2,ss,3); }
      __builtin_amdgcn_s_barrier();
      __builtin_amdgcn_s_setprio(1);
      #pragma unroll
      for (int ks=0;ks<2;ks++)
        #pragma unroll
        for (int j=0;j<2;j++)
          #pragma unroll
          for (int ni=0;ni<4;ni++)
            acc[2+j][ni] = __builtin_amdgcn_mfma_f32_16x16x32_bf16(
                af[j][ks], breg[ni][ks], acc[2+j][ni], 0, 0, 0);
      __builtin_amdgcn_s_setprio(0);
      if (stg)               { asm volatile("s_waitcnt vmcnt(6)" ::: "memory"); }
      else if (m+1 < NT)     { asm volatile("s_waitcnt vmcnt(0)" ::: "memory"); }
      __builtin_amdgcn_s_barrier();
    }
  }
  #undef SGA
  #undef SGB

  // ---- coalesced bf16 epilogue via LDS, single pass -------------------------
  __syncthreads();
  float bs[4];
  #pragma unroll
  for (int ni=0;ni<4;ni++) bs[ni] = bias[n0 + wn*64 + ni*16 + l16];
  constexpr int LDE = 264;
  #pragma unroll
  for (int mi=0; mi<4; mi++)
    #pragma unroll
    for (int ni=0;ni<4;ni++)
      #pragma unroll
      for (int i=0;i<4;i++){
        float vv = acc[mi][ni][i] + bs[ni];
        if constexpr (RELU) vv = fmaxf(vv, 0.f);
        S[(wm*64 + mi*16 + 4*g16 + i)*LDE + wn*64 + ni*16 + l16] = f2b(vv);
      }
  __syncthreads();
  #pragma unroll
  for (int cc=0; cc<8; cc++){
    const int c = t + cc*512;              // 0..4095 (128 rows x 32 chunks)
    const int R = c >> 5, ck = c & 31;
    uint4 v = *(const uint4*)&S[R*LDE + ck*8];
    *(uint4*)&outp[(m0 + R)*N + n0 + ck*8] = v;
  }
}

// ---------------- attention: one block per (b,h) ----------------------------
// R13 version (116 VGPR, 4 waves/SIMD). R14 lesson: Vt anti-conflict swizzle
// cut conflicts 4.7e6->1.9e6 but +16 VGPR -> 3 waves/SIMD; latency-bound
// kernel -> occupancy beats bank conflicts. Do not re-add.
__global__ __launch_bounds__(256) void attn_kernel(const u16* __restrict__ qkv,
    const int* __restrict__ mask, u16* __restrict__ ctx){
  __shared__ __align__(16) u16 Vt[64*232];
  __shared__ __align__(16) u16 Ps[4*16*232];
  __shared__ float maskadd[208];
  const int bh = blockIdx.x, b = bh>>3, h = bh&7;
  const int t = threadIdx.x, lane = t&63, w = t>>6;
  const int g16 = lane>>4, l16 = lane&15;

  for (int i=t; i<1856; i+=256) ((uint4*)Vt)[i] = make_uint4(0,0,0,0);
  for (int i=t; i<1856; i+=256) ((uint4*)Ps)[i] = make_uint4(0,0,0,0);
  __syncthreads();

  for (int idx = t; idx < 1600; idx += 256){
    const int s = idx >> 3, d0 = (idx & 7) * 8;
    uint4 v4 = *(const uint4*)&qkv[((size_t)(b*200+s))*1536 + 1024 + h*64 + d0];
    const u16* e = (const u16*)&v4;
    #pragma unroll
    for (int j=0;j<8;j++) Vt[(d0+j)*232 + s] = e[j];
  }
  if (t < 208) maskadd[t] = (t < 200 && mask[b*200+t] != 0) ? 0.f : -1e30f;
  __syncthreads();

  u16* Pw = Ps + w*16*232;
  const float scale = 0.125f;

  for (int rt = w; rt < 13; rt += 4){
    const int rbase = rt*16;
    f32x4 sc[13];
    #pragma unroll
    for (int ct=0;ct<13;ct++) sc[ct] = zero4();

    #pragma unroll
    for (int ks=0; ks<64; ks+=32){
      const int ko = ks + 8*g16;
      const size_t qrow = (size_t)(b*200) + rbase + l16;
      bf16x8 aq = *(const bf16x8*)&qkv[qrow*1536 + h*64 + ko];
      #pragma unroll
      for (int ct=0; ct<13; ct++){
        const size_t krow = (size_t)(b*200) + ct*16 + l16;
        bf16x8 bk8 = *(const bf16x8*)&qkv[krow*1536 + 512 + h*64 + ko];
        sc[ct] = __builtin_amdgcn_mfma_f32_16x16x32_bf16(aq, bk8, sc[ct], 0,0,0);
      }
    }

    float mx[4] = {-1e30f,-1e30f,-1e30f,-1e30f};
    #pragma unroll
    for (int ct=0;ct<13;ct++){
      float ma = maskadd[ct*16 + l16];
      #pragma unroll
      for (int i=0;i<4;i++){
        float s0 = sc[ct][i]*scale + ma;
        sc[ct][i] = s0;
        mx[i] = fmaxf(mx[i], s0);
      }
    }
    #pragma unroll
    for (int i=0;i<4;i++)
      for (int d=1; d<16; d<<=1) mx[i] = fmaxf(mx[i], __shfl_xor(mx[i], d));
    float sm[4] = {0.f,0.f,0.f,0.f};
    #pragma unroll
    for (int ct=0;ct<13;ct++)
      #pragma unroll
      for (int i=0;i<4;i++){
        float e = __expf(sc[ct][i] - mx[i]);
        sc[ct][i] = e; sm[i] += e;
      }
    #pragma unroll
    for (int i=0;i<4;i++)
      for (int d=1; d<16; d<<=1) sm[i] += __shfl_xor(sm[i], d);
    float rs[4];
    #pragma unroll
    for (int i=0;i<4;i++) rs[i] = 1.f/sm[i];

    #pragma unroll
    for (int ct=0;ct<13;ct++)
      #pragma unroll
      for (int i=0;i<4;i++)
        Pw[(4*g16+i)*232 + ct*16 + l16] = f2b(sc[ct][i]);
    asm volatile("s_waitcnt lgkmcnt(0)" ::: "memory");

    f32x4 cacc[4];
    #pragma unroll
    for (int ni=0;ni<4;ni++) cacc[ni] = zero4();
    #pragma unroll
    for (int kt=0; kt<7; kt++){
      const int ko = kt*32 + 8*g16;
      bf16x8 ap = *(const bf16x8*)&Pw[l16*232 + ko];
      #pragma unroll
      for (int ni=0; ni<4; ni++){
        bf16x8 bv8 = *(const bf16x8*)&Vt[(ni*16 + l16)*232 + ko];
        cacc[ni] = __builtin_amdgcn_mfma_f32_16x16x32_bf16(ap, bv8, cacc[ni], 0,0,0);
      }
    }
    #pragma unroll
    for (int ni=0;ni<4;ni++)
      #pragma unroll
      for (int i=0;i<4;i++){
        const int r = rbase + 4*g16 + i;
        if (r < 200)
          ctx[((size_t)(b*200+r))*512 + h*64 + ni*16 + l16] = f2b(cacc[ni][i]*rs[i]);
      }
  }
}

// ------- residual + LayerNorm, bf16 stream (one wave per 512-row) -----------
template<bool RESID, bool F32OUT>
__global__ __launch_bounds__(256) void add_ln_bf(const u16* __restrict__ xin,
    const u16* __restrict__ yin, const float* __restrict__ gam,
    const float* __restrict__ bet, u16* __restrict__ bfout,
    float* __restrict__ fout){
  const int r = blockIdx.x*4 + (threadIdx.x>>6);
  const int lane = threadIdx.x & 63;
  const size_t base = (size_t)r*512 + lane*8;
  uint4 xv = *(const uint4*)&xin[base];
  const u16* xp = (const u16*)&xv;
  float vv[8];
  #pragma unroll
  for (int j=0;j<8;j++) vv[j] = b2f(xp[j]);
  if constexpr (RESID){
    uint4 yv = *(const uint4*)&yin[base];
    const u16* yp = (const u16*)&yv;
    #pragma unroll
    for (int j=0;j<8;j++) vv[j] += b2f(yp[j]);
  }
  float s=0.f, q2=0.f;
  #pragma unroll
  for (int j=0;j<8;j++){ s += vv[j]; q2 += vv[j]*vv[j]; }
  #pragma unroll
  for (int d=1; d<64; d<<=1){ s += __shfl_xor(s,d); q2 += __shfl_xor(q2,d); }
  const float mean = s * (1.f/512.f);
  const float var  = q2 * (1.f/512.f) - mean*mean;
  const float rstd = rsqrtf(var + 1e-5f);
  const int col = lane*8;
  float4 g0 = *(const float4*)&gam[col], g1 = *(const float4*)&gam[col+4];
  float4 b0 = *(const float4*)&bet[col], b1 = *(const float4*)&bet[col+4];
  float gg[8] = {g0.x,g0.y,g0.z,g0.w,g1.x,g1.y,g1.z,g1.w};
  float bb[8] = {b0.x,b0.y,b0.z,b0.w,b1.x,b1.y,b1.z,b1.w};
  float o[8];
  #pragma unroll
  for (int j=0;j<8;j++) o[j] = (vv[j]-mean)*rstd*gg[j] + bb[j];
  if constexpr (F32OUT){
    float4 w0 = {o[0],o[1],o[2],o[3]}, w1 = {o[4],o[5],o[6],o[7]};
    *(float4*)&fout[base] = w0;
    *(float4*)&fout[base+4] = w1;
  } else {
    union { u16 pk[8]; uint4 v; } u;
    #pragma unroll
    for (int j=0;j<8;j++) u.pk[j] = f2b(o[j]);
    *(uint4*)&bfout[base] = u.v;
  }
}

// ---------------------------------------------------------------------------
extern "C" void kernel_launch(void* const* d_in, const int* in_sizes, int n_in,
                              void* d_out, int out_size, void* d_ws, size_t ws_size,
                              hipStream_t stream){
  const float* traj = (const float*)d_in[0];
  const int*   mask = (const int*)  d_in[1];
  const float* pe   = (const float*)d_in[2];
  const float* We   = (const float*)d_in[3];
  const float* be   = (const float*)d_in[4];
  const float* Wq   = (const float*)d_in[5];
  const float* bq   = (const float*)d_in[6];
  const float* Wk   = (const float*)d_in[7];
  const float* bk   = (const float*)d_in[8];
  const float* Wv   = (const float*)d_in[9];
  const float* bv   = (const float*)d_in[10];
  const float* Wo   = (const float*)d_in[11];
  const float* bo   = (const float*)d_in[12];
  const float* ln1g = (const float*)d_in[13];
  const float* ln1b = (const float*)d_in[14];
  const float* W1   = (const float*)d_in[15];
  const float* b1   = (const float*)d_in[16];
  const float* W2   = (const float*)d_in[17];
  const float* b2   = (const float*)d_in[18];
  const float* ln2g = (const float*)d_in[19];
  const float* ln2b = (const float*)d_in[20];
  const float* lnfg = (const float*)d_in[21];
  const float* lnfb = (const float*)d_in[22];

  const size_t PROJ = 512*512, FFW = (size_t)512*2048, TOK = (size_t)25600*512;
  const size_t QKVW = (size_t)1536*512;
  u16* Wcat = (u16*)d_ws;                         // 6 x [1536][512]
  u16* Wot  = Wcat + 6*QKVW;                      // 6 x [512][512]
  u16* W1t  = Wot + 6*PROJ;                       // 6 x [2048][512]
  u16* W2t  = W1t + 6*FFW;                        // 6 x [512][2048]
  u16* xs   = W2t + 6*FFW;                        // bf16 residual stream
  u16* R    = xs + TOK;                           // [25600][2048] scratch
  u16* qkvb = R;                                  // [25600][1536]
  u16* ffb  = R;                                  // [25600][2048]
  u16* cb   = R + (size_t)25600*2048;             // [25600][512] ctx
  u16* yb   = cb + TOK;                           // [25600][512] proj/ff2 out
  float* bcat = (float*)(yb + TOK);               // 6 x [1536]

  dim3 B256(256);
  transpose_k<512,512,(long long)1536*512><<<dim3(16,16,6), B256, 0, stream>>>(Wq, Wcat);
  transpose_k<512,512,(long long)1536*512><<<dim3(16,16,6), B256, 0, stream>>>(Wk, Wcat + 512*512);
  transpose_k<512,512,(long long)1536*512><<<dim3(16,16,6), B256, 0, stream>>>(Wv, Wcat + 1024*512);
  transpose_k<512,512,(long long)512*512> <<<dim3(16,16,6), B256, 0, stream>>>(Wo, Wot);
  transpose_k<512,2048,(long long)512*2048><<<dim3(16,64,6), B256, 0, stream>>>(W1, W1t);
  transpose_k<2048,512,(long long)512*2048><<<dim3(64,16,6), B256, 0, stream>>>(W2, W2t);
  concat_bias<<<36, B256, 0, stream>>>(bq, bk, bv, bcat);

  embed_kernel<<<6400, B256, 0, stream>>>(traj, We, be, pe, xs);

  for (int i=0; i<6; i++){
    gemm128<512,6,false><<<1200, 512, 0, stream>>>(xs, Wcat + (size_t)i*QKVW, bcat + i*1536, qkvb, 1200);
    attn_kernel<<<1024, B256, 0, stream>>>(qkvb, mask, cb);
    gemm256<512,2,false><<<200, 512, 0, stream>>>(cb, Wot + (size_t)i*PROJ, bo + i*512, yb, 200);
    add_ln_bf<true,false><<<6400, B256, 0, stream>>>(xs, yb, ln1g + i*512, ln1b + i*512, xs, nullptr);
    gemm128<512,8,true><<<1600, 512, 0, stream>>>(xs, W1t + (size_t)i*FFW, b1 + i*2048, ffb, 1600);
    gemm256<2048,2,false><<<200, 512, 0, stream>>>(ffb, W2t + (size_t)i*FFW, b2 + i*512, yb, 200);
    add_ln_bf<true,false><<<6400, B256, 0, stream>>>(xs, yb, ln2g + i*512, ln2b + i*512, xs, nullptr);
  }
  add_ln_bf<false,true><<<6400, B256, 0, stream>>>(xs, xs, lnfg, lnfb, nullptr, (float*)d_out);
}

// Round 18
// 1600.326 us; speedup vs baseline: 1.1132x; 1.0025x over previous
//
#include <hip/hip_runtime.h>

typedef unsigned short u16;
typedef __bf16 bf16x8 __attribute__((ext_vector_type(8)));
typedef float f32x4 __attribute__((ext_vector_type(4)));

#define DEV __device__ __forceinline__

DEV u16 f2b(float f){
  union { float f; unsigned u; } v; v.f = f;
  unsigned r = v.u + 0x7FFFu + ((v.u >> 16) & 1u);
  return (u16)(r >> 16);
}
DEV float b2f(u16 h){
  union { unsigned u; float f; } v; v.u = ((unsigned)h) << 16; return v.f;
}

DEV f32x4 zero4(){ f32x4 z; z[0]=0.f; z[1]=0.f; z[2]=0.f; z[3]=0.f; return z; }

// async 16B global -> LDS (dest = wave-uniform base + lane*16)
DEV void gload16(const u16* g, const u16* l){
  __builtin_amdgcn_global_load_lds(
      (const __attribute__((address_space(1))) unsigned int*)g,
      (__attribute__((address_space(3))) unsigned int*)l, 16, 0, 0);
}

// ---------------- transpose + fp32->bf16: dst[n*K+k] = bf16(src[k*N+n]) -----
template<int K, int N, long long DSTR>
__global__ __launch_bounds__(256) void transpose_k(const float* __restrict__ src,
                                                   u16* __restrict__ dst){
  __shared__ float tile[32][33];
  const int z = blockIdx.z;
  const float* s = src + (size_t)z*K*N;
  u16* d = dst + (size_t)z*DSTR;
  const int k0 = blockIdx.x*32, n0 = blockIdx.y*32;
  const int tx = threadIdx.x & 31, ty = threadIdx.x >> 5;
  #pragma unroll
  for (int j=0;j<32;j+=8) tile[ty+j][tx] = s[(size_t)(k0+ty+j)*N + n0+tx];
  __syncthreads();
  #pragma unroll
  for (int j=0;j<32;j+=8) d[(size_t)(n0+ty+j)*K + k0+tx] = f2b(tile[tx][ty+j]);
}

// ---------------- bias concat for fused QKV --------------------------------
__global__ __launch_bounds__(256) void concat_bias(const float* __restrict__ bq,
    const float* __restrict__ bk, const float* __restrict__ bv,
    float* __restrict__ bcat){
  int i = blockIdx.x*256 + threadIdx.x;            // over 6*1536
  int l = i / 1536, c = i % 1536;
  float v = (c < 512) ? bq[l*512 + c]
          : (c < 1024) ? bk[l*512 + c - 512]
                       : bv[l*512 + c - 1024];
  bcat[i] = v;
}

// ------- embedding (vectorized 8/thread): x = traj@W_emb + b_emb + pe -------
__global__ __launch_bounds__(256) void embed_kernel(const float* __restrict__ traj,
    const float* __restrict__ We, const float* __restrict__ be,
    const float* __restrict__ pe, u16* __restrict__ xb){
  size_t g = (size_t)blockIdx.x*256 + threadIdx.x;   // over 25600*64 groups
  const int d0 = (int)(g & 63) * 8;
  const size_t tk = g >> 6;
  const float t0 = traj[tk*2], t1 = traj[tk*2+1];
  union { u16 pk[8]; uint4 v; } u;
  #pragma unroll
  for (int j=0;j<8;j++){
    const int d = d0 + j;
    u.pk[j] = f2b(t0*We[d] + t1*We[512+d] + be[d] + pe[200*512 + d]);
  }
  *(uint4*)&xb[tk*512 + d0] = u.v;
}

// ===================== 256x256 8-phase GEMM (T2+T3+T4+T5) ====================
// R13 trunk. Used for Wo, FF1, FF2. FF1 R16 lesson: the 128x256 tile has 1.5x
// staging-per-FLOP -> per-tile 0.58T, 7 passes == 4T: no quantization gain.
template<int K, int NTI, bool RELU>
__global__ __launch_bounds__(512, 2) void gemm256(const u16* __restrict__ A,
    const u16* __restrict__ Bt, const float* __restrict__ bias,
    u16* __restrict__ outp, int nwg){
  constexpr int N = NTI*256;
  constexpr int NT = K/64;              // K-tiles (even for K=512/2048)
  __shared__ __align__(16) u16 S[65536];
  const int t = threadIdx.x, lane = t&63, w = t>>6;
  const int l16 = lane&15, g16 = lane>>4;
  const int wm = w>>2, wn = w&3;

  // bijective XCD swizzle (m204)
  const int orig = blockIdx.x;
  const int qq = nwg>>3, rr = nwg&7, xc = orig&7, oo = orig>>3;
  const int wg = (xc<rr ? xc*(qq+1) : rr*(qq+1)+(xc-rr)*qq) + oo;
  const int mt = wg / NTI, ntl = wg % NTI;
  const size_t m0 = (size_t)mt*256, n0 = (size_t)ntl*256;
  const u16* Ab = A + m0*K;
  const u16* Bb = Bt + n0*K;

  const int srow = t>>3;
  const int scol = 8*((t&7) ^ ((t>>3)&7));
  const int kx = (l16&7)<<3;            // read-side XOR (u16 units)

  const u16* gA[4] = {Ab + (size_t)srow*K + scol,       Ab + (size_t)(64+srow)*K + scol,
                      Ab + (size_t)(128+srow)*K + scol, Ab + (size_t)(192+srow)*K + scol};
  const u16* gB[4] = {Bb + (size_t)srow*K + scol,       Bb + (size_t)(64+srow)*K + scol,
                      Bb + (size_t)(128+srow)*K + scol, Bb + (size_t)(192+srow)*K + scol};

  f32x4 acc[8][4];
  #pragma unroll
  for (int i=0;i<8;i++)
    #pragma unroll
    for (int j=0;j<4;j++) acc[i][j] = zero4();

  #define STG(gp, kb, region, half)                                         \
    { gload16(gp[2*(half)]   + (kb), &S[(region) + (half)*8192 + w*512]);   \
      gload16(gp[2*(half)+1] + (kb), &S[(region) + (half)*8192 + 4096 + w*512]); }

  STG(gA, 0, 0, 0);      STG(gA, 0, 0, 1);
  STG(gB, 0, 16384, 0);  STG(gB, 0, 16384, 1);
  STG(gB, 64, 49152, 0); STG(gB, 64, 49152, 1);
  asm volatile("s_waitcnt vmcnt(4)" ::: "memory");
  __builtin_amdgcn_s_barrier();

  bf16x8 breg[4][2];

  #define PHASE(AB, BB, Q, LOADB, STG_STMT, VMW, ENDBAR)                    \
  {                                                                         \
    bf16x8 af[2][2];                                                        \
    _Pragma("unroll")                                                       \
    for (int ks=0;ks<2;ks++){                                               \
      _Pragma("unroll")                                                     \
      for (int j=0;j<2;j++)                                                 \
        af[j][ks] = *(const bf16x8*)&S[(AB) + (wm*128 + (2*(Q)+j)*16 + l16)*64 \
                                        + ((ks*32 + g16*8) ^ kx)];          \
      if (LOADB){                                                           \
        _Pragma("unroll")                                                   \
        for (int ni=0;ni<4;ni++)                                            \
          breg[ni][ks] = *(const bf16x8*)&S[(BB) + (wn*64 + ni*16 + l16)*64 \
                                             + ((ks*32 + g16*8) ^ kx)];     \
      }                                                                     \
    }                                                                       \
    STG_STMT;                                                               \
    __builtin_amdgcn_s_barrier();                                           \
    __builtin_amdgcn_s_setprio(1);                                          \
    _Pragma("unroll")                                                       \
    for (int ks=0;ks<2;ks++){                                               \
      _Pragma("unroll")                                                     \
      for (int j=0;j<2;j++){                                                \
        _Pragma("unroll")                                                   \
        for (int ni=0;ni<4;ni++)                                            \
          acc[2*(Q)+j][ni] = __builtin_amdgcn_mfma_f32_16x16x32_bf16(       \
              af[j][ks], breg[ni][ks], acc[2*(Q)+j][ni], 0, 0, 0);          \
      }                                                                     \
    }                                                                       \
    __builtin_amdgcn_s_setprio(0);                                          \
    VMW;                                                                    \
    if (ENDBAR) __builtin_amdgcn_s_barrier();                               \
  }

  for (int it=0; it<NT/2; ++it){
    const bool last = (it == NT/2 - 1);
    const int k1 = 2*it+1, k2 = 2*it+2, k3 = 2*it+3;   // k2,k3 used iff !last
    PHASE(0,     16384, 0, true,  STG(gA, k1*64, 32768, 0), ((void)0), 0);
    PHASE(0,     16384, 1, false, STG(gA, k1*64, 32768, 1), ((void)0), 0);
    PHASE(0,     16384, 2, false, if(!last){ STG(gB, k2*64, 16384, 0) }, ((void)0), 0);
    PHASE(0,     16384, 3, false, if(!last){ STG(gB, k2*64, 16384, 1) },
          if(last){ asm volatile("s_waitcnt vmcnt(0)" ::: "memory"); }
          else    { asm volatile("s_waitcnt vmcnt(4)" ::: "memory"); }, 1);
    PHASE(32768, 49152, 0, true,  if(!last){ STG(gA, k2*64, 0, 0) }, ((void)0), 0);
    PHASE(32768, 49152, 1, false, if(!last){ STG(gA, k2*64, 0, 1) }, ((void)0), 0);
    PHASE(32768, 49152, 2, false, if(!last){ STG(gB, k3*64, 49152, 0) }, ((void)0), 0);
    PHASE(32768, 49152, 3, false, if(!last){ STG(gB, k3*64, 49152, 1) },
          if(!last){ asm volatile("s_waitcnt vmcnt(4)" ::: "memory"); }, 1);
  }
  #undef PHASE
  #undef STG

  __syncthreads();
  float bs[4];
  #pragma unroll
  for (int ni=0;ni<4;ni++) bs[ni] = bias[n0 + wn*64 + ni*16 + l16];
  constexpr int LDE = 264;                           // 256 + 8 pad (u16)
  #pragma unroll
  for (int pass=0; pass<2; ++pass){
    const int miB = pass*4;
    #pragma unroll
    for (int miL=0; miL<4; miL++){
      #pragma unroll
      for (int ni=0;ni<4;ni++){
        #pragma unroll
        for (int i=0;i<4;i++){
          float vv = acc[miB+miL][ni][i] + bs[ni];
          if constexpr (RELU) vv = fmaxf(vv, 0.f);
          S[(wm*64 + miL*16 + 4*g16 + i)*LDE + wn*64 + ni*16 + l16] = f2b(vv);
        }
      }
    }
    __syncthreads();
    #pragma unroll
    for (int cc=0; cc<8; cc++){
      const int c = t + cc*512;
      const int R = c >> 5, ck = c & 31;
      uint4 v = *(const uint4*)&S[R*LDE + ck*8];
      const size_t grow = m0 + (size_t)(R>>6)*128 + miB*16 + (R&63);
      *(uint4*)&outp[grow*N + n0 + ck*8] = v;
    }
    if (pass == 0) __syncthreads();
  }
}

// ===================== 128x256 2-phase GEMM (half-T tile) ====================
// R16-verified. Used for QKV only (1200 tiles -> better CU fill than 600x256^2;
// FF1 showed the 1.5x staging-per-FLOP cancels the quantization gain).
template<int K, int NTI, bool RELU>
__global__ __launch_bounds__(512, 2) void gemm128(const u16* __restrict__ A,
    const u16* __restrict__ Bt, const float* __restrict__ bias,
    u16* __restrict__ outp, int nwg){
  constexpr int N = NTI*256;
  constexpr int NT = K/64;
  __shared__ __align__(16) u16 S[73728];
  const int t = threadIdx.x, lane = t&63, w = t>>6;
  const int l16 = lane&15, g16 = lane>>4;
  const int wm = w>>2, wn = w&3;

  // bijective XCD swizzle (m204); nwg % 8 == 0 for all uses
  const int orig = blockIdx.x;
  const int qq = nwg>>3, rr = nwg&7, xc = orig&7, oo = orig>>3;
  const int wg = (xc<rr ? xc*(qq+1) : rr*(qq+1)+(xc-rr)*qq) + oo;
  const int mt = wg / NTI, ntl = wg % NTI;
  const size_t m0 = (size_t)mt*128, n0 = (size_t)ntl*256;
  const u16* Ab = A + m0*K;
  const u16* Bb = Bt + n0*K;

  const int srow = t>>3;
  const int scol = 8*((t&7) ^ ((t>>3)&7));
  const int kx = (l16&7)<<3;

  const u16* gA[2] = {Ab + (size_t)srow*K + scol, Ab + (size_t)(64+srow)*K + scol};
  const u16* gB[4] = {Bb + (size_t)srow*K + scol,       Bb + (size_t)(64+srow)*K + scol,
                      Bb + (size_t)(128+srow)*K + scol, Bb + (size_t)(192+srow)*K + scol};

  f32x4 acc[4][4];
  #pragma unroll
  for (int i=0;i<4;i++)
    #pragma unroll
    for (int j=0;j<4;j++) acc[i][j] = zero4();

  #define SGA(kt, sl, li) gload16(gA[li] + (kt)*64, &S[(sl)*8192 + (li)*4096 + w*512])
  #define SGB(kt, sl, li) gload16(gB[li] + (kt)*64, &S[24576 + (sl)*16384 + (li)*4096 + w*512])

  SGA(0,0,0); SGA(0,0,1); SGB(0,0,0); SGB(0,0,1); SGB(0,0,2); SGB(0,0,3);
  SGA(1,1,0); SGA(1,1,1); SGB(1,1,0); SGB(1,1,1); SGB(1,1,2); SGB(1,1,3);
  asm volatile("s_waitcnt vmcnt(6)" ::: "memory");
  __builtin_amdgcn_s_barrier();

  bf16x8 breg[4][2];

  for (int m=0; m<NT; ++m){
    const int cs = m % 3, ss = (m+2) % 3;
    const int sA = cs*8192, sB = 24576 + cs*16384;
    const bool stg = (m+2 < NT);
    const int k2 = m+2;
    {
      bf16x8 af[2][2];
      #pragma unroll
      for (int ks=0;ks<2;ks++){
        #pragma unroll
        for (int j=0;j<2;j++)
          af[j][ks] = *(const bf16x8*)&S[sA + (wm*64 + j*16 + l16)*64
                                          + ((ks*32 + g16*8) ^ kx)];
        #pragma unroll
        for (int ni=0;ni<4;ni++)
          breg[ni][ks] = *(const bf16x8*)&S[sB + (wn*64 + ni*16 + l16)*64
                                             + ((ks*32 + g16*8) ^ kx)];
      }
      if (stg){ SGA(k2,ss,0); SGA(k2,ss,1); SGB(k2,ss,0); }
      __builtin_amdgcn_s_barrier();
      __builtin_amdgcn_s_setprio(1);
      #pragma unroll
      for (int ks=0;ks<2;ks++)
        #pragma unroll
        for (int j=0;j<2;j++)
          #pragma unroll
          for (int ni=0;ni<4;ni++)
            acc[j][ni] = __builtin_amdgcn_mfma_f32_16x16x32_bf16(
                af[j][ks], breg[ni][ks], acc[j][ni], 0, 0, 0);
      __builtin_amdgcn_s_setprio(0);
    }
    {
      bf16x8 af[2][2];
      #pragma unroll
      for (int ks=0;ks<2;ks++)
        #pragma unroll
        for (int j=0;j<2;j++)
          af[j][ks] = *(const bf16x8*)&S[sA + (wm*64 + (2+j)*16 + l16)*64
                                          + ((ks*32 + g16*8) ^ kx)];
      if (stg){ SGB(k2,ss,1); SGB(k2,ss,2); SGB(k2,ss,3); }
      __builtin_amdgcn_s_barrier();
      __builtin_amdgcn_s_setprio(1);
      #pragma unroll
      for (int ks=0;ks<2;ks++)
        #pragma unroll
        for (int j=0;j<2;j++)
          #pragma unroll
          for (int ni=0;ni<4;ni++)
            acc[2+j][ni] = __builtin_amdgcn_mfma_f32_16x16x32_bf16(
                af[j][ks], breg[ni][ks], acc[2+j][ni], 0, 0, 0);
      __builtin_amdgcn_s_setprio(0);
      if (stg)               { asm volatile("s_waitcnt vmcnt(6)" ::: "memory"); }
      else if (m+1 < NT)     { asm volatile("s_waitcnt vmcnt(0)" ::: "memory"); }
      __builtin_amdgcn_s_barrier();
    }
  }
  #undef SGA
  #undef SGB

  __syncthreads();
  float bs[4];
  #pragma unroll
  for (int ni=0;ni<4;ni++) bs[ni] = bias[n0 + wn*64 + ni*16 + l16];
  constexpr int LDE = 264;
  #pragma unroll
  for (int mi=0; mi<4; mi++)
    #pragma unroll
    for (int ni=0;ni<4;ni++)
      #pragma unroll
      for (int i=0;i<4;i++){
        float vv = acc[mi][ni][i] + bs[ni];
        if constexpr (RELU) vv = fmaxf(vv, 0.f);
        S[(wm*64 + mi*16 + 4*g16 + i)*LDE + wn*64 + ni*16 + l16] = f2b(vv);
      }
  __syncthreads();
  #pragma unroll
  for (int cc=0; cc<8; cc++){
    const int c = t + cc*512;
    const int R = c >> 5, ck = c & 31;
    uint4 v = *(const uint4*)&S[R*LDE + ck*8];
    *(uint4*)&outp[(m0 + R)*N + n0 + ck*8] = v;
  }
}

// ---------------- attention: one block per (b,h) ----------------------------
// R13 version (116 VGPR, 4 waves/SIMD). R14 lesson: Vt anti-conflict swizzle
// cost +16 VGPR -> 3 waves/SIMD; latency-bound kernel -> occupancy wins.
__global__ __launch_bounds__(256) void attn_kernel(const u16* __restrict__ qkv,
    const int* __restrict__ mask, u16* __restrict__ ctx){
  __shared__ __align__(16) u16 Vt[64*232];
  __shared__ __align__(16) u16 Ps[4*16*232];
  __shared__ float maskadd[208];
  const int bh = blockIdx.x, b = bh>>3, h = bh&7;
  const int t = threadIdx.x, lane = t&63, w = t>>6;
  const int g16 = lane>>4, l16 = lane&15;

  for (int i=t; i<1856; i+=256) ((uint4*)Vt)[i] = make_uint4(0,0,0,0);
  for (int i=t; i<1856; i+=256) ((uint4*)Ps)[i] = make_uint4(0,0,0,0);
  __syncthreads();

  for (int idx = t; idx < 1600; idx += 256){
    const int s = idx >> 3, d0 = (idx & 7) * 8;
    uint4 v4 = *(const uint4*)&qkv[((size_t)(b*200+s))*1536 + 1024 + h*64 + d0];
    const u16* e = (const u16*)&v4;
    #pragma unroll
    for (int j=0;j<8;j++) Vt[(d0+j)*232 + s] = e[j];
  }
  if (t < 208) maskadd[t] = (t < 200 && mask[b*200+t] != 0) ? 0.f : -1e30f;
  __syncthreads();

  u16* Pw = Ps + w*16*232;
  const float scale = 0.125f;

  for (int rt = w; rt < 13; rt += 4){
    const int rbase = rt*16;
    f32x4 sc[13];
    #pragma unroll
    for (int ct=0;ct<13;ct++) sc[ct] = zero4();

    #pragma unroll
    for (int ks=0; ks<64; ks+=32){
      const int ko = ks + 8*g16;
      const size_t qrow = (size_t)(b*200) + rbase + l16;
      bf16x8 aq = *(const bf16x8*)&qkv[qrow*1536 + h*64 + ko];
      #pragma unroll
      for (int ct=0; ct<13; ct++){
        const size_t krow = (size_t)(b*200) + ct*16 + l16;
        bf16x8 bk8 = *(const bf16x8*)&qkv[krow*1536 + 512 + h*64 + ko];
        sc[ct] = __builtin_amdgcn_mfma_f32_16x16x32_bf16(aq, bk8, sc[ct], 0,0,0);
      }
    }

    float mx[4] = {-1e30f,-1e30f,-1e30f,-1e30f};
    #pragma unroll
    for (int ct=0;ct<13;ct++){
      float ma = maskadd[ct*16 + l16];
      #pragma unroll
      for (int i=0;i<4;i++){
        float s0 = sc[ct][i]*scale + ma;
        sc[ct][i] = s0;
        mx[i] = fmaxf(mx[i], s0);
      }
    }
    #pragma unroll
    for (int i=0;i<4;i++)
      for (int d=1; d<16; d<<=1) mx[i] = fmaxf(mx[i], __shfl_xor(mx[i], d));
    float sm[4] = {0.f,0.f,0.f,0.f};
    #pragma unroll
    for (int ct=0;ct<13;ct++)
      #pragma unroll
      for (int i=0;i<4;i++){
        float e = __expf(sc[ct][i] - mx[i]);
        sc[ct][i] = e; sm[i] += e;
      }
    #pragma unroll
    for (int i=0;i<4;i++)
      for (int d=1; d<16; d<<=1) sm[i] += __shfl_xor(sm[i], d);
    float rs[4];
    #pragma unroll
    for (int i=0;i<4;i++) rs[i] = 1.f/sm[i];

    #pragma unroll
    for (int ct=0;ct<13;ct++)
      #pragma unroll
      for (int i=0;i<4;i++)
        Pw[(4*g16+i)*232 + ct*16 + l16] = f2b(sc[ct][i]);
    asm volatile("s_waitcnt lgkmcnt(0)" ::: "memory");

    f32x4 cacc[4];
    #pragma unroll
    for (int ni=0;ni<4;ni++) cacc[ni] = zero4();
    #pragma unroll
    for (int kt=0; kt<7; kt++){
      const int ko = kt*32 + 8*g16;
      bf16x8 ap = *(const bf16x8*)&Pw[l16*232 + ko];
      #pragma unroll
      for (int ni=0; ni<4; ni++){
        bf16x8 bv8 = *(const bf16x8*)&Vt[(ni*16 + l16)*232 + ko];
        cacc[ni] = __builtin_amdgcn_mfma_f32_16x16x32_bf16(ap, bv8, cacc[ni], 0,0,0);
      }
    }
    #pragma unroll
    for (int ni=0;ni<4;ni++)
      #pragma unroll
      for (int i=0;i<4;i++){
        const int r = rbase + 4*g16 + i;
        if (r < 200)
          ctx[((size_t)(b*200+r))*512 + h*64 + ni*16 + l16] = f2b(cacc[ni][i]*rs[i]);
      }
  }
}

// ------- residual + LayerNorm, bf16 stream (one wave per 512-row) -----------
template<bool RESID, bool F32OUT>
__global__ __launch_bounds__(256) void add_ln_bf(const u16* __restrict__ xin,
    const u16* __restrict__ yin, const float* __restrict__ gam,
    const float* __restrict__ bet, u16* __restrict__ bfout,
    float* __restrict__ fout){
  const int r = blockIdx.x*4 + (threadIdx.x>>6);
  const int lane = threadIdx.x & 63;
  const size_t base = (size_t)r*512 + lane*8;
  uint4 xv = *(const uint4*)&xin[base];
  const u16* xp = (const u16*)&xv;
  float vv[8];
  #pragma unroll
  for (int j=0;j<8;j++) vv[j] = b2f(xp[j]);
  if constexpr (RESID){
    uint4 yv = *(const uint4*)&yin[base];
    const u16* yp = (const u16*)&yv;
    #pragma unroll
    for (int j=0;j<8;j++) vv[j] += b2f(yp[j]);
  }
  float s=0.f, q2=0.f;
  #pragma unroll
  for (int j=0;j<8;j++){ s += vv[j]; q2 += vv[j]*vv[j]; }
  #pragma unroll
  for (int d=1; d<64; d<<=1){ s += __shfl_xor(s,d); q2 += __shfl_xor(q2,d); }
  const float mean = s * (1.f/512.f);
  const float var  = q2 * (1.f/512.f) - mean*mean;
  const float rstd = rsqrtf(var + 1e-5f);
  const int col = lane*8;
  float4 g0 = *(const float4*)&gam[col], g1 = *(const float4*)&gam[col+4];
  float4 b0 = *(const float4*)&bet[col], b1 = *(const float4*)&bet[col+4];
  float gg[8] = {g0.x,g0.y,g0.z,g0.w,g1.x,g1.y,g1.z,g1.w};
  float bb[8] = {b0.x,b0.y,b0.z,b0.w,b1.x,b1.y,b1.z,b1.w};
  float o[8];
  #pragma unroll
  for (int j=0;j<8;j++) o[j] = (vv[j]-mean)*rstd*gg[j] + bb[j];
  if constexpr (F32OUT){
    float4 w0 = {o[0],o[1],o[2],o[3]}, w1 = {o[4],o[5],o[6],o[7]};
    *(float4*)&fout[base] = w0;
    *(float4*)&fout[base+4] = w1;
  } else {
    union { u16 pk[8]; uint4 v; } u;
    #pragma unroll
    for (int j=0;j<8;j++) u.pk[j] = f2b(o[j]);
    *(uint4*)&bfout[base] = u.v;
  }
}

// ---------------------------------------------------------------------------
extern "C" void kernel_launch(void* const* d_in, const int* in_sizes, int n_in,
                              void* d_out, int out_size, void* d_ws, size_t ws_size,
                              hipStream_t stream){
  const float* traj = (const float*)d_in[0];
  const int*   mask = (const int*)  d_in[1];
  const float* pe   = (const float*)d_in[2];
  const float* We   = (const float*)d_in[3];
  const float* be   = (const float*)d_in[4];
  const float* Wq   = (const float*)d_in[5];
  const float* bq   = (const float*)d_in[6];
  const float* Wk   = (const float*)d_in[7];
  const float* bk   = (const float*)d_in[8];
  const float* Wv   = (const float*)d_in[9];
  const float* bv   = (const float*)d_in[10];
  const float* Wo   = (const float*)d_in[11];
  const float* bo   = (const float*)d_in[12];
  const float* ln1g = (const float*)d_in[13];
  const float* ln1b = (const float*)d_in[14];
  const float* W1   = (const float*)d_in[15];
  const float* b1   = (const float*)d_in[16];
  const float* W2   = (const float*)d_in[17];
  const float* b2   = (const float*)d_in[18];
  const float* ln2g = (const float*)d_in[19];
  const float* ln2b = (const float*)d_in[20];
  const float* lnfg = (const float*)d_in[21];
  const float* lnfb = (const float*)d_in[22];

  const size_t PROJ = 512*512, FFW = (size_t)512*2048, TOK = (size_t)25600*512;
  const size_t QKVW = (size_t)1536*512;
  u16* Wcat = (u16*)d_ws;                         // 6 x [1536][512]
  u16* Wot  = Wcat + 6*QKVW;                      // 6 x [512][512]
  u16* W1t  = Wot + 6*PROJ;                       // 6 x [2048][512]
  u16* W2t  = W1t + 6*FFW;                        // 6 x [512][2048]
  u16* xs   = W2t + 6*FFW;                        // bf16 residual stream
  u16* R    = xs + TOK;                           // [25600][2048] scratch
  u16* qkvb = R;                                  // [25600][1536]
  u16* ffb  = R;                                  // [25600][2048]
  u16* cb   = R + (size_t)25600*2048;             // [25600][512] ctx
  u16* yb   = cb + TOK;                           // [25600][512] proj/ff2 out
  float* bcat = (float*)(yb + TOK);               // 6 x [1536]

  dim3 B256(256);
  transpose_k<512,512,(long long)1536*512><<<dim3(16,16,6), B256, 0, stream>>>(Wq, Wcat);
  transpose_k<512,512,(long long)1536*512><<<dim3(16,16,6), B256, 0, stream>>>(Wk, Wcat + 512*512);
  transpose_k<512,512,(long long)1536*512><<<dim3(16,16,6), B256, 0, stream>>>(Wv, Wcat + 1024*512);
  transpose_k<512,512,(long long)512*512> <<<dim3(16,16,6), B256, 0, stream>>>(Wo, Wot);
  transpose_k<512,2048,(long long)512*2048><<<dim3(16,64,6), B256, 0, stream>>>(W1, W1t);
  transpose_k<2048,512,(long long)512*2048><<<dim3(64,16,6), B256, 0, stream>>>(W2, W2t);
  concat_bias<<<36, B256, 0, stream>>>(bq, bk, bv, bcat);

  embed_kernel<<<6400, B256, 0, stream>>>(traj, We, be, pe, xs);

  for (int i=0; i<6; i++){
    gemm128<512,6,false><<<1200, 512, 0, stream>>>(xs, Wcat + (size_t)i*QKVW, bcat + i*1536, qkvb, 1200);
    attn_kernel<<<1024, B256, 0, stream>>>(qkvb, mask, cb);
    gemm256<512,2,false><<<200, 512, 0, stream>>>(cb, Wot + (size_t)i*PROJ, bo + i*512, yb, 200);
    add_ln_bf<true,false><<<6400, B256, 0, stream>>>(xs, yb, ln1g + i*512, ln1b + i*512, xs, nullptr);
    gemm256<512,8,true><<<800, 512, 0, stream>>>(xs, W1t + (size_t)i*FFW, b1 + i*2048, ffb, 800);
    gemm256<2048,2,false><<<200, 512, 0, stream>>>(ffb, W2t + (size_t)i*FFW, b2 + i*512, yb, 200);
    add_ln_bf<true,false><<<6400, B256, 0, stream>>>(xs, yb, ln2g + i*512, ln2b + i*512, xs, nullptr);
  }
  add_ln_bf<false,true><<<6400, B256, 0, stream>>>(xs, xs, lnfg, lnfb, nullptr, (float*)d_out);
}